// Round 5
// baseline (386.185 us; speedup 1.0000x reference)
//
#include <hip/hip_runtime.h>
#include <hip/hip_bf16.h>
#include <stdint.h>

#define NODES 50000
#define EDGES 800000
#define DIM 256
#define NREL 8
#define NJ (NREL * DIM)  // 2048 combined output cols (r*256+o)

typedef unsigned short u16;
typedef __attribute__((ext_vector_type(8))) __bf16 bf16x8;
typedef __attribute__((ext_vector_type(4))) float f32x4;

#define GLOBAL_AS __attribute__((address_space(1)))
#define LDS_AS __attribute__((address_space(3)))

__device__ __forceinline__ u16 f2bf(float f) {
  uint32_t u = __builtin_bit_cast(uint32_t, f);
  u += 0x7FFFu + ((u >> 16) & 1u);  // RNE; inputs finite
  return (u16)(u >> 16);
}
__device__ __forceinline__ float bf2f(u16 u) {
  uint32_t t = (uint32_t)u << 16;
  return __builtin_bit_cast(float, t);
}

__global__ void k_cvt(const float* __restrict__ in, u16* __restrict__ outp, int n4) {
  int i = blockIdx.x * blockDim.x + threadIdx.x;
  if (i >= n4) return;
  float4 v = ((const float4*)in)[i];
  ushort4 o;
  o.x = f2bf(v.x); o.y = f2bf(v.y); o.z = f2bf(v.z); o.w = f2bf(v.w);
  ((ushort4*)outp)[i] = o;
}

// ---------------- Tier A: dense GEMM -> dst-sorted gather-reduce ----------------

// h[n][j] = sum_i xb[n][i] * wb[j][i].  392 m-tiles (padded to 8x49) x 16 j-tiles.
// XCD-chunked mapping (T1): xcd=bid&7 owns m-tiles [xcd*49, xcd*49+49); within the
// band, j runs in two groups of 8 (B working set 2MB stays L2-resident; h stores are
// non-temporal so the write stream doesn't evict it), A-panel's 8 blocks consecutive.
__global__ __launch_bounds__(256) void k_gemm(
    const u16* __restrict__ xb, const u16* __restrict__ wb, u16* __restrict__ h)
{
  const int bid = blockIdx.x;
  const int xcd = bid & 7;
  const int idx = bid >> 3;          // 0..783
  const int jg  = idx / 392;         // 0,1
  const int r2  = idx - jg * 392;
  const int m   = xcd * 49 + (r2 >> 3);
  const int mbase = m * 128;
  if (mbase >= NODES) return;
  const int jbase = (jg * 8 + (r2 & 7)) * 128;

  __shared__ __align__(16) u16 s_a[128 * 32];  // 8KB
  __shared__ __align__(16) u16 s_b[128 * 32];  // 8KB

  const int tid = threadIdx.x;
  const int lane = tid & 63;
  const int wv = tid >> 6;
  const int wr = wv >> 1, wc = wv & 1;
  const int swz = (lane & 3) ^ ((lane >> 2) & 3) ^ (lane >> 4);  // 16B-chunk idx

  f32x4 acc[4][4];
#pragma unroll
  for (int mm = 0; mm < 4; ++mm)
#pragma unroll
    for (int n = 0; n < 4; ++n) acc[mm][n] = f32x4{0.f, 0.f, 0.f, 0.f};

  const int arow0 = wv * 32;  // this wave stages rows [arow0, arow0+32)

  for (int ks = 0; ks < 8; ++ks) {
#pragma unroll
    for (int c2 = 0; c2 < 2; ++c2) {
      const int rowb = arow0 + c2 * 16;
      const int row  = rowb + (lane >> 2);
      const int ar = min(mbase + row, NODES - 1);  // clamp last tile
      const u16* ga = xb + ((size_t)ar << 8) + (ks << 5) + (swz << 3);
      __builtin_amdgcn_global_load_lds((const GLOBAL_AS uint32_t*)ga,
                                       (LDS_AS uint32_t*)(s_a + rowb * 32), 16, 0, 0);
      const u16* gb = wb + ((size_t)(jbase + row) << 8) + (ks << 5) + (swz << 3);
      __builtin_amdgcn_global_load_lds((const GLOBAL_AS uint32_t*)gb,
                                       (LDS_AS uint32_t*)(s_b + rowb * 32), 16, 0, 0);
    }
    __syncthreads();

    bf16x8 af[4], bfr[4];
#pragma unroll
    for (int mm = 0; mm < 4; ++mm)
      af[mm] = *(const bf16x8*)(s_a + (wr * 64 + mm * 16 + (lane & 15)) * 32 + swz * 8);
#pragma unroll
    for (int n = 0; n < 4; ++n)
      bfr[n] = *(const bf16x8*)(s_b + (wc * 64 + n * 16 + (lane & 15)) * 32 + swz * 8);
#pragma unroll
    for (int mm = 0; mm < 4; ++mm)
#pragma unroll
      for (int n = 0; n < 4; ++n)
        acc[mm][n] = __builtin_amdgcn_mfma_f32_16x16x32_bf16(af[mm], bfr[n], acc[mm][n], 0, 0, 0);
    __syncthreads();
  }

  // store bf16 h (non-temporal: consumed once from L3 by k_reduce).
  // D layout: col=lane&15, row=(lane>>4)*4+q (m89-verified)
  const int colb = jbase + wc * 64 + (lane & 15);
#pragma unroll
  for (int mm = 0; mm < 4; ++mm) {
#pragma unroll
    for (int q = 0; q < 4; ++q) {
      const int grow = mbase + wr * 64 + mm * 16 + (lane >> 4) * 4 + q;
      if (grow < NODES) {
        u16* hp = h + (size_t)grow * NJ + colb;
#pragma unroll
        for (int n = 0; n < 4; ++n)
          __builtin_nontemporal_store(f2bf(acc[mm][n][q]), hp + n * 16);
      }
    }
  }
}

// ---- counting sort by dst (50K bins; ~16-way contention is harmless) ----

__global__ void k_hist2(const int* __restrict__ edst, int* __restrict__ cnt) {
  int e = blockIdx.x * blockDim.x + threadIdx.x;
  if (e < EDGES) atomicAdd(&cnt[edst[e]], 1);
}

// Single-block exclusive scan of cnt[50000] -> row_ptr/cur (replaces 3 kernels).
#define SCAN_T 1024
#define SCAN_PER 49  // 1024*49 = 50176 >= 50000
__global__ __launch_bounds__(SCAN_T) void k_scan_all(
    const int* __restrict__ cnt, int* __restrict__ row_ptr, int* __restrict__ cur)
{
  __shared__ int tsum[SCAN_T];
  const int t = threadIdx.x;
  const int base = t * SCAN_PER;
  int s = 0;
  for (int k = 0; k < SCAN_PER; ++k) {
    const int i = base + k;
    s += (i < NODES) ? cnt[i] : 0;
  }
  tsum[t] = s;
  __syncthreads();
  for (int o = 1; o < SCAN_T; o <<= 1) {  // Hillis-Steele inclusive
    const int u = (t >= o) ? tsum[t - o] : 0;
    __syncthreads();
    tsum[t] += u;
    __syncthreads();
  }
  int run = (t == 0) ? 0 : tsum[t - 1];
  for (int k = 0; k < SCAN_PER; ++k) {
    const int i = base + k;
    if (i < NODES) {
      row_ptr[i] = run; cur[i] = run;
      run += cnt[i];
    }
  }
  if (t == SCAN_T - 1) row_ptr[NODES] = tsum[SCAN_T - 1];  // == EDGES
}

__global__ void k_scatter2(const int* __restrict__ esrc, const int* __restrict__ edst,
                           const int* __restrict__ et, int* __restrict__ cur,
                           int* __restrict__ sg) {
  int e = blockIdx.x * blockDim.x + threadIdx.x;
  if (e < EDGES) {
    int p = atomicAdd(&cur[edst[e]], 1);  // in-bin order irrelevant (sum commutes)
    sg[p] = esrc[e] * NREL + et[e];       // h row index
  }
}

// One wave per dst node: gather ~deg(16) rows of h (512B each), f32-accumulate,
// +bias, single coalesced float4 row write (nt). 8-deep gather unroll for MLP.
__global__ __launch_bounds__(256) void k_reduce(
    const u16* __restrict__ h, const int* __restrict__ row_ptr,
    const int* __restrict__ sg, const float* __restrict__ bias,
    float* __restrict__ out)
{
  const int wid = (int)((blockIdx.x * blockDim.x + threadIdx.x) >> 6);
  if (wid >= NODES) return;
  const int lane = threadIdx.x & 63;
  const int lo = row_ptr[wid], hi = row_ptr[wid + 1];
  const u16* hb = h + lane * 4;

  float a0 = 0.f, a1 = 0.f, a2 = 0.f, a3 = 0.f;
  int e = lo;
  for (; e + 8 <= hi; e += 8) {  // 8 independent 512B gathers in flight
    const ushort4 v0 = *(const ushort4*)(hb + ((size_t)sg[e] << 8));
    const ushort4 v1 = *(const ushort4*)(hb + ((size_t)sg[e + 1] << 8));
    const ushort4 v2 = *(const ushort4*)(hb + ((size_t)sg[e + 2] << 8));
    const ushort4 v3 = *(const ushort4*)(hb + ((size_t)sg[e + 3] << 8));
    const ushort4 v4 = *(const ushort4*)(hb + ((size_t)sg[e + 4] << 8));
    const ushort4 v5 = *(const ushort4*)(hb + ((size_t)sg[e + 5] << 8));
    const ushort4 v6 = *(const ushort4*)(hb + ((size_t)sg[e + 6] << 8));
    const ushort4 v7 = *(const ushort4*)(hb + ((size_t)sg[e + 7] << 8));
    a0 += ((bf2f(v0.x) + bf2f(v1.x)) + (bf2f(v2.x) + bf2f(v3.x))) +
          ((bf2f(v4.x) + bf2f(v5.x)) + (bf2f(v6.x) + bf2f(v7.x)));
    a1 += ((bf2f(v0.y) + bf2f(v1.y)) + (bf2f(v2.y) + bf2f(v3.y))) +
          ((bf2f(v4.y) + bf2f(v5.y)) + (bf2f(v6.y) + bf2f(v7.y)));
    a2 += ((bf2f(v0.z) + bf2f(v1.z)) + (bf2f(v2.z) + bf2f(v3.z))) +
          ((bf2f(v4.z) + bf2f(v5.z)) + (bf2f(v6.z) + bf2f(v7.z)));
    a3 += ((bf2f(v0.w) + bf2f(v1.w)) + (bf2f(v2.w) + bf2f(v3.w))) +
          ((bf2f(v4.w) + bf2f(v5.w)) + (bf2f(v6.w) + bf2f(v7.w)));
  }
  for (; e + 2 <= hi; e += 2) {
    const ushort4 v0 = *(const ushort4*)(hb + ((size_t)sg[e] << 8));
    const ushort4 v1 = *(const ushort4*)(hb + ((size_t)sg[e + 1] << 8));
    a0 += bf2f(v0.x) + bf2f(v1.x);
    a1 += bf2f(v0.y) + bf2f(v1.y);
    a2 += bf2f(v0.z) + bf2f(v1.z);
    a3 += bf2f(v0.w) + bf2f(v1.w);
  }
  if (e < hi) {
    const ushort4 v = *(const ushort4*)(hb + ((size_t)sg[e] << 8));
    a0 += bf2f(v.x); a1 += bf2f(v.y); a2 += bf2f(v.z); a3 += bf2f(v.w);
  }
  const float4 b = ((const float4*)bias)[lane];
  f32x4 o = {a0 + b.x, a1 + b.y, a2 + b.z, a3 + b.w};
  __builtin_nontemporal_store(o, (f32x4*)out + (size_t)wid * 64 + lane);
}

// ---------------- Tier B: round-2 path (per-relation gathered GEMM + atomics) ----------------

__global__ void k_init_out(float* __restrict__ out, const float* __restrict__ bias) {
  int i = blockIdx.x * blockDim.x + threadIdx.x;
  ((float4*)out)[i] = ((const float4*)bias)[i & 63];
}
__global__ void k_zero8(int* __restrict__ meta) {
  if (threadIdx.x < 8) meta[threadIdx.x] = 0;
}
#define SORT_BLOCKS 256
#define SORT_CHUNK ((EDGES + SORT_BLOCKS - 1) / SORT_BLOCKS)
__global__ void k_hist(const int* __restrict__ et, int* __restrict__ meta) {
  __shared__ int lh[NREL];
  if (threadIdx.x < NREL) lh[threadIdx.x] = 0;
  __syncthreads();
  const int lo = blockIdx.x * SORT_CHUNK, hi = min(EDGES, lo + SORT_CHUNK);
  for (int e = lo + threadIdx.x; e < hi; e += blockDim.x) atomicAdd(&lh[et[e]], 1);
  __syncthreads();
  if (threadIdx.x < NREL && lh[threadIdx.x]) atomicAdd(&meta[threadIdx.x], lh[threadIdx.x]);
}
__global__ void k_scan(int* __restrict__ meta) {
  if (threadIdx.x == 0) {
    int s = 0;
    for (int r = 0; r < NREL; ++r) { meta[8 + r] = s; meta[17 + r] = s; s += meta[r]; }
    meta[16] = s;
  }
}
__global__ void k_scatter(const int* __restrict__ et, int* __restrict__ meta,
                          int* __restrict__ perm) {
  __shared__ int lh[NREL];
  __shared__ int lc[NREL];
  if (threadIdx.x < NREL) lh[threadIdx.x] = 0;
  __syncthreads();
  const int lo = blockIdx.x * SORT_CHUNK, hi = min(EDGES, lo + SORT_CHUNK);
  for (int e = lo + threadIdx.x; e < hi; e += blockDim.x) atomicAdd(&lh[et[e]], 1);
  __syncthreads();
  if (threadIdx.x < NREL) {
    const int c = lh[threadIdx.x];
    lc[threadIdx.x] = c ? atomicAdd(&meta[17 + threadIdx.x], c) : 0;
  }
  __syncthreads();
  for (int e = lo + threadIdx.x; e < hi; e += blockDim.x) {
    const int p = atomicAdd(&lc[et[e]], 1);
    perm[p] = e;
  }
}
__global__ __launch_bounds__(256) void k_gemm_b(
    const u16* __restrict__ xb, const u16* __restrict__ wb,
    const int* __restrict__ perm, const int* __restrict__ meta,
    const int* __restrict__ esrc, const int* __restrict__ edst,
    float* __restrict__ out)
{
  const int r = blockIdx.z;
  const int estart = meta[8 + r], eend = meta[9 + r];
  const int base = estart + (int)blockIdx.x * 128;
  if (base >= eend) return;
  const int mcount = min(128, eend - base);
  const int ny = blockIdx.y;
  __shared__ int s_src[128];
  __shared__ int s_dst[128];
  __shared__ __align__(16) u16 s_a[128 * 32];
  __shared__ __align__(16) u16 s_b[128 * 32];
  const int tid = threadIdx.x;
  if (tid < 128) {
    int sv = 0, dv = 0;
    if (tid < mcount) { int e = perm[base + tid]; sv = esrc[e]; dv = edst[e]; }
    s_src[tid] = sv; s_dst[tid] = dv;
  }
  __syncthreads();
  const int lane = tid & 63;
  const int wv = tid >> 6;
  const int wr = wv >> 1, wc = wv & 1;
  const int swz = (lane & 3) ^ ((lane >> 2) & 3) ^ (lane >> 4);
  f32x4 acc[4][4];
#pragma unroll
  for (int m = 0; m < 4; ++m)
#pragma unroll
    for (int n = 0; n < 4; ++n) acc[m][n] = f32x4{0.f, 0.f, 0.f, 0.f};
  const int arow0 = wv * 32;
  const size_t wbase = ((size_t)r << 16) + ((size_t)ny << 15);
  for (int ks = 0; ks < 8; ++ks) {
#pragma unroll
    for (int c2 = 0; c2 < 2; ++c2) {
      const int rowb = arow0 + c2 * 16;
      const int row  = rowb + (lane >> 2);
      const u16* ga = xb + ((size_t)s_src[row] << 8) + (ks << 5) + (swz << 3);
      __builtin_amdgcn_global_load_lds((const GLOBAL_AS uint32_t*)ga,
                                       (LDS_AS uint32_t*)(s_a + rowb * 32), 16, 0, 0);
      const u16* gb = wb + wbase + ((size_t)row << 8) + (ks << 5) + (swz << 3);
      __builtin_amdgcn_global_load_lds((const GLOBAL_AS uint32_t*)gb,
                                       (LDS_AS uint32_t*)(s_b + rowb * 32), 16, 0, 0);
    }
    __syncthreads();
    bf16x8 af[4], bfr[4];
#pragma unroll
    for (int m = 0; m < 4; ++m)
      af[m] = *(const bf16x8*)(s_a + (wr * 64 + m * 16 + (lane & 15)) * 32 + swz * 8);
#pragma unroll
    for (int n = 0; n < 4; ++n)
      bfr[n] = *(const bf16x8*)(s_b + (wc * 64 + n * 16 + (lane & 15)) * 32 + swz * 8);
#pragma unroll
    for (int m = 0; m < 4; ++m)
#pragma unroll
      for (int n = 0; n < 4; ++n)
        acc[m][n] = __builtin_amdgcn_mfma_f32_16x16x32_bf16(af[m], bfr[n], acc[m][n], 0, 0, 0);
    __syncthreads();
  }
  const int colb = ny * 128 + wc * 64 + (lane & 15);
#pragma unroll
  for (int m = 0; m < 4; ++m) {
#pragma unroll
    for (int q = 0; q < 4; ++q) {
      const int rl = wr * 64 + m * 16 + (lane >> 4) * 4 + q;
      if (rl < mcount) {
        float* op = out + (size_t)s_dst[rl] * DIM + colb;
#pragma unroll
        for (int n = 0; n < 4; ++n) atomicAdd(op + n * 16, acc[m][n][q]);
      }
    }
  }
}

// Tier C: correctness-only fallback.
__global__ void k_naive(const float* __restrict__ x, const float* __restrict__ w,
                        const int* __restrict__ esrc, const int* __restrict__ edst,
                        const int* __restrict__ et, float* __restrict__ out)
{
  const int lane = threadIdx.x & 63;
  int gw = (blockIdx.x * blockDim.x + threadIdx.x) >> 6;
  const int nw = (gridDim.x * blockDim.x) >> 6;
  for (int e = gw; e < EDGES; e += nw) {
    const int s = esrc[e], d = edst[e], r = et[e];
    const float* xr = x + (size_t)s * DIM;
    const float* wr0 = w + (size_t)r * DIM * DIM;
    float a[4] = {0.f, 0.f, 0.f, 0.f};
    for (int i = 0; i < DIM; ++i) {
      const float xv = xr[i];
#pragma unroll
      for (int c = 0; c < 4; ++c) a[c] += xv * wr0[(size_t)(lane + c * 64) * DIM + i];
    }
#pragma unroll
    for (int c = 0; c < 4; ++c) atomicAdd(&out[(size_t)d * DIM + lane + c * 64], a[c]);
  }
}

extern "C" void kernel_launch(void* const* d_in, const int* in_sizes, int n_in,
                              void* d_out, int out_size, void* d_ws, size_t ws_size,
                              hipStream_t stream) {
  const float* x    = (const float*)d_in[0];
  const float* w    = (const float*)d_in[1];
  const float* bias = (const float*)d_in[2];
  const int* eidx   = (const int*)d_in[3];
  const int* et     = (const int*)d_in[4];
  const int* esrc = eidx;
  const int* edst = eidx + EDGES;
  float* out = (float*)d_out;

  auto pad = [](size_t v) { return (v + 255) & ~(size_t)255; };

  // Tier A layout
  size_t needA = 0;
  const size_t a_xb = needA;  needA = pad(needA + (size_t)NODES * DIM * 2);
  const size_t a_wb = needA;  needA = pad(needA + (size_t)NREL * DIM * DIM * 2);
  const size_t a_h  = needA;  needA = pad(needA + (size_t)NODES * NJ * 2);
  const size_t a_cnt = needA; needA = pad(needA + (size_t)NODES * 4);
  const size_t a_rp  = needA; needA = pad(needA + ((size_t)NODES + 1) * 4);
  const size_t a_cur = needA; needA = pad(needA + (size_t)NODES * 4);
  const size_t a_sg  = needA; needA = pad(needA + (size_t)EDGES * 4);

  // Tier B layout
  size_t needB = 0;
  const size_t b_xb = needB;   needB = pad(needB + (size_t)NODES * DIM * 2);
  const size_t b_wb = needB;   needB = pad(needB + (size_t)NREL * DIM * DIM * 2);
  const size_t b_perm = needB; needB = pad(needB + (size_t)EDGES * 4);
  const size_t b_meta = needB; needB = pad(needB + 64 * 4);

  char* ws = (char*)d_ws;
  if (needA <= ws_size) {
    u16* xb = (u16*)(ws + a_xb);
    u16* wb = (u16*)(ws + a_wb);
    u16* h  = (u16*)(ws + a_h);
    int* cnt = (int*)(ws + a_cnt);
    int* rp  = (int*)(ws + a_rp);
    int* cur = (int*)(ws + a_cur);
    int* sg  = (int*)(ws + a_sg);

    k_cvt<<<12500, 256, 0, stream>>>(x, xb, NODES * DIM / 4);
    k_cvt<<<512, 256, 0, stream>>>(w, wb, NREL * DIM * DIM / 4);
    (void)hipMemsetAsync(cnt, 0, (size_t)NODES * 4, stream);
    k_hist2<<<3125, 256, 0, stream>>>(edst, cnt);
    k_scan_all<<<1, SCAN_T, 0, stream>>>(cnt, rp, cur);
    k_scatter2<<<3125, 256, 0, stream>>>(esrc, edst, et, cur, sg);
    k_gemm<<<392 * 16, 256, 0, stream>>>(xb, wb, h);
    k_reduce<<<(NODES * 64 + 255) / 256, 256, 0, stream>>>(h, rp, sg, bias, out);
  } else if (needB <= ws_size) {
    u16* xb  = (u16*)(ws + b_xb);
    u16* wbb = (u16*)(ws + b_wb);
    int* perm = (int*)(ws + b_perm);
    int* meta = (int*)(ws + b_meta);
    k_init_out<<<12500, 256, 0, stream>>>(out, bias);
    k_cvt<<<12500, 256, 0, stream>>>(x, xb, NODES * DIM / 4);
    k_cvt<<<512, 256, 0, stream>>>(w, wbb, NREL * DIM * DIM / 4);
    k_zero8<<<1, 64, 0, stream>>>(meta);
    k_hist<<<SORT_BLOCKS, 256, 0, stream>>>(et, meta);
    k_scan<<<1, 1, 0, stream>>>(meta);
    k_scatter<<<SORT_BLOCKS, 256, 0, stream>>>(et, meta, perm);
    dim3 g(6250, 2, NREL);
    k_gemm_b<<<g, 256, 0, stream>>>(xb, wbb, perm, meta, esrc, edst, out);
  } else {
    k_init_out<<<12500, 256, 0, stream>>>(out, bias);
    k_naive<<<2048, 256, 0, stream>>>(x, w, esrc, edst, et, out);
  }
}

// Round 6
// 272.573 us; speedup vs baseline: 1.4168x; 1.4168x over previous
//
#include <hip/hip_runtime.h>
#include <hip/hip_bf16.h>
#include <stdint.h>

#define NODES 50000
#define EDGES 800000
#define DIM 256
#define NREL 8
#define NJ (NREL * DIM)  // 2048 combined output cols (r*256+o)

typedef unsigned short u16;
typedef __attribute__((ext_vector_type(8))) __bf16 bf16x8;
typedef __attribute__((ext_vector_type(4))) float f32x4;

#define GLOBAL_AS __attribute__((address_space(1)))
#define LDS_AS __attribute__((address_space(3)))

__device__ __forceinline__ u16 f2bf(float f) {
  uint32_t u = __builtin_bit_cast(uint32_t, f);
  u += 0x7FFFu + ((u >> 16) & 1u);  // RNE; inputs finite
  return (u16)(u >> 16);
}
__device__ __forceinline__ float bf2f(u16 u) {
  uint32_t t = (uint32_t)u << 16;
  return __builtin_bit_cast(float, t);
}

__global__ void k_cvt(const float* __restrict__ in, u16* __restrict__ outp, int n4) {
  int i = blockIdx.x * blockDim.x + threadIdx.x;
  if (i >= n4) return;
  float4 v = ((const float4*)in)[i];
  ushort4 o;
  o.x = f2bf(v.x); o.y = f2bf(v.y); o.z = f2bf(v.z); o.w = f2bf(v.w);
  ((ushort4*)outp)[i] = o;
}

// ---------------- Tier A: dense GEMM -> dst-sorted gather-reduce ----------------

// h[n][j] = sum_i xb[n][i] * wb[j][i].  392 m-tiles (padded to 8x49) x 16 j-tiles.
// XCD-chunked mapping (T1): xcd=bid&7 owns m-tiles [xcd*49, xcd*49+49); within the
// band, j runs in two groups of 8 (B working set 2MB stays L2-resident; h stores are
// non-temporal so the write stream doesn't evict it), A-panel's 8 blocks consecutive.
__global__ __launch_bounds__(256) void k_gemm(
    const u16* __restrict__ xb, const u16* __restrict__ wb, u16* __restrict__ h)
{
  const int bid = blockIdx.x;
  const int xcd = bid & 7;
  const int idx = bid >> 3;          // 0..783
  const int jg  = idx / 392;         // 0,1
  const int r2  = idx - jg * 392;
  const int m   = xcd * 49 + (r2 >> 3);
  const int mbase = m * 128;
  if (mbase >= NODES) return;
  const int jbase = (jg * 8 + (r2 & 7)) * 128;

  __shared__ __align__(16) u16 s_a[128 * 32];  // 8KB
  __shared__ __align__(16) u16 s_b[128 * 32];  // 8KB

  const int tid = threadIdx.x;
  const int lane = tid & 63;
  const int wv = tid >> 6;
  const int wr = wv >> 1, wc = wv & 1;
  const int swz = (lane & 3) ^ ((lane >> 2) & 3) ^ (lane >> 4);  // 16B-chunk idx

  f32x4 acc[4][4];
#pragma unroll
  for (int mm = 0; mm < 4; ++mm)
#pragma unroll
    for (int n = 0; n < 4; ++n) acc[mm][n] = f32x4{0.f, 0.f, 0.f, 0.f};

  const int arow0 = wv * 32;  // this wave stages rows [arow0, arow0+32)

  for (int ks = 0; ks < 8; ++ks) {
#pragma unroll
    for (int c2 = 0; c2 < 2; ++c2) {
      const int rowb = arow0 + c2 * 16;
      const int row  = rowb + (lane >> 2);
      const int ar = min(mbase + row, NODES - 1);  // clamp last tile
      const u16* ga = xb + ((size_t)ar << 8) + (ks << 5) + (swz << 3);
      __builtin_amdgcn_global_load_lds((const GLOBAL_AS uint32_t*)ga,
                                       (LDS_AS uint32_t*)(s_a + rowb * 32), 16, 0, 0);
      const u16* gb = wb + ((size_t)(jbase + row) << 8) + (ks << 5) + (swz << 3);
      __builtin_amdgcn_global_load_lds((const GLOBAL_AS uint32_t*)gb,
                                       (LDS_AS uint32_t*)(s_b + rowb * 32), 16, 0, 0);
    }
    __syncthreads();

    bf16x8 af[4], bfr[4];
#pragma unroll
    for (int mm = 0; mm < 4; ++mm)
      af[mm] = *(const bf16x8*)(s_a + (wr * 64 + mm * 16 + (lane & 15)) * 32 + swz * 8);
#pragma unroll
    for (int n = 0; n < 4; ++n)
      bfr[n] = *(const bf16x8*)(s_b + (wc * 64 + n * 16 + (lane & 15)) * 32 + swz * 8);
#pragma unroll
    for (int mm = 0; mm < 4; ++mm)
#pragma unroll
      for (int n = 0; n < 4; ++n)
        acc[mm][n] = __builtin_amdgcn_mfma_f32_16x16x32_bf16(af[mm], bfr[n], acc[mm][n], 0, 0, 0);
    __syncthreads();
  }

  // store bf16 h (non-temporal: consumed once from L3 by k_reduce).
  // D layout: col=lane&15, row=(lane>>4)*4+q (m89-verified)
  const int colb = jbase + wc * 64 + (lane & 15);
#pragma unroll
  for (int mm = 0; mm < 4; ++mm) {
#pragma unroll
    for (int q = 0; q < 4; ++q) {
      const int grow = mbase + wr * 64 + mm * 16 + (lane >> 4) * 4 + q;
      if (grow < NODES) {
        u16* hp = h + (size_t)grow * NJ + colb;
#pragma unroll
        for (int n = 0; n < 4; ++n)
          __builtin_nontemporal_store(f2bf(acc[mm][n][q]), hp + n * 16);
      }
    }
  }
}

// ---- counting sort by dst (50K bins). Scan = 3 small multi-block kernels:
// round-5's single-block k_scan_all was 124us at 0.15% occupancy (60:1 loss
// vs the ~2us/launch it saved — G11: never serialize 200KB onto one CU). ----
#define SCAN_BLOCKS 196  // ceil(50000/256)

__global__ void k_hist2(const int* __restrict__ edst, int* __restrict__ cnt) {
  int e = blockIdx.x * blockDim.x + threadIdx.x;
  if (e < EDGES) atomicAdd(&cnt[edst[e]], 1);
}
__global__ void k_bsum(const int* __restrict__ cnt, int* __restrict__ bs) {
  int i = blockIdx.x * blockDim.x + threadIdx.x;
  int v = (i < NODES) ? cnt[i] : 0;
#pragma unroll
  for (int o = 32; o; o >>= 1) v += __shfl_down(v, o);
  __shared__ int wsum[4];
  if ((threadIdx.x & 63) == 0) wsum[threadIdx.x >> 6] = v;
  __syncthreads();
  if (threadIdx.x == 0) bs[blockIdx.x] = wsum[0] + wsum[1] + wsum[2] + wsum[3];
}
__global__ void k_bscan(int* __restrict__ bs) {  // exclusive scan of SCAN_BLOCKS, 1 block
  __shared__ int tmp[SCAN_BLOCKS];
  int t = threadIdx.x;
  if (t < SCAN_BLOCKS) tmp[t] = bs[t];
  __syncthreads();
  if (t == 0) {
    int s = 0;
    for (int i = 0; i < SCAN_BLOCKS; ++i) { int c = tmp[i]; tmp[i] = s; s += c; }
  }
  __syncthreads();
  if (t < SCAN_BLOCKS) bs[t] = tmp[t];
}
__global__ void k_scan2(const int* __restrict__ cnt, const int* __restrict__ bs,
                        int* __restrict__ row_ptr, int* __restrict__ cur) {
  int t = threadIdx.x;
  int i = blockIdx.x * blockDim.x + t;
  int v = (i < NODES) ? cnt[i] : 0;
  __shared__ int tmp[256];
  tmp[t] = v;
  __syncthreads();
  for (int o = 1; o < 256; o <<= 1) {  // Hillis-Steele inclusive
    int u = (t >= o) ? tmp[t - o] : 0;
    __syncthreads();
    tmp[t] += u;
    __syncthreads();
  }
  int val = bs[blockIdx.x] + tmp[t] - v;  // exclusive
  if (i <= NODES) row_ptr[i] = val;       // row_ptr[NODES] lands on EDGES
  if (i < NODES) cur[i] = val;
}
__global__ void k_scatter2(const int* __restrict__ esrc, const int* __restrict__ edst,
                           const int* __restrict__ et, int* __restrict__ cur,
                           int* __restrict__ sg) {
  int e = blockIdx.x * blockDim.x + threadIdx.x;
  if (e < EDGES) {
    int p = atomicAdd(&cur[edst[e]], 1);  // in-bin order irrelevant (sum commutes)
    sg[p] = esrc[e] * NREL + et[e];       // h row index
  }
}

// One wave per dst node: gather ~deg(16) rows of h (512B each), f32-accumulate,
// +bias, single coalesced row write (nt). 8-deep gather unroll for MLP.
__global__ __launch_bounds__(256) void k_reduce(
    const u16* __restrict__ h, const int* __restrict__ row_ptr,
    const int* __restrict__ sg, const float* __restrict__ bias,
    float* __restrict__ out)
{
  const int wid = (int)((blockIdx.x * blockDim.x + threadIdx.x) >> 6);
  if (wid >= NODES) return;
  const int lane = threadIdx.x & 63;
  const int lo = row_ptr[wid], hi = row_ptr[wid + 1];
  const u16* hb = h + lane * 4;

  float a0 = 0.f, a1 = 0.f, a2 = 0.f, a3 = 0.f;
  int e = lo;
  for (; e + 8 <= hi; e += 8) {  // 8 independent 512B gathers in flight
    const ushort4 v0 = *(const ushort4*)(hb + ((size_t)sg[e] << 8));
    const ushort4 v1 = *(const ushort4*)(hb + ((size_t)sg[e + 1] << 8));
    const ushort4 v2 = *(const ushort4*)(hb + ((size_t)sg[e + 2] << 8));
    const ushort4 v3 = *(const ushort4*)(hb + ((size_t)sg[e + 3] << 8));
    const ushort4 v4 = *(const ushort4*)(hb + ((size_t)sg[e + 4] << 8));
    const ushort4 v5 = *(const ushort4*)(hb + ((size_t)sg[e + 5] << 8));
    const ushort4 v6 = *(const ushort4*)(hb + ((size_t)sg[e + 6] << 8));
    const ushort4 v7 = *(const ushort4*)(hb + ((size_t)sg[e + 7] << 8));
    a0 += ((bf2f(v0.x) + bf2f(v1.x)) + (bf2f(v2.x) + bf2f(v3.x))) +
          ((bf2f(v4.x) + bf2f(v5.x)) + (bf2f(v6.x) + bf2f(v7.x)));
    a1 += ((bf2f(v0.y) + bf2f(v1.y)) + (bf2f(v2.y) + bf2f(v3.y))) +
          ((bf2f(v4.y) + bf2f(v5.y)) + (bf2f(v6.y) + bf2f(v7.y)));
    a2 += ((bf2f(v0.z) + bf2f(v1.z)) + (bf2f(v2.z) + bf2f(v3.z))) +
          ((bf2f(v4.z) + bf2f(v5.z)) + (bf2f(v6.z) + bf2f(v7.z)));
    a3 += ((bf2f(v0.w) + bf2f(v1.w)) + (bf2f(v2.w) + bf2f(v3.w))) +
          ((bf2f(v4.w) + bf2f(v5.w)) + (bf2f(v6.w) + bf2f(v7.w)));
  }
  for (; e + 2 <= hi; e += 2) {
    const ushort4 v0 = *(const ushort4*)(hb + ((size_t)sg[e] << 8));
    const ushort4 v1 = *(const ushort4*)(hb + ((size_t)sg[e + 1] << 8));
    a0 += bf2f(v0.x) + bf2f(v1.x);
    a1 += bf2f(v0.y) + bf2f(v1.y);
    a2 += bf2f(v0.z) + bf2f(v1.z);
    a3 += bf2f(v0.w) + bf2f(v1.w);
  }
  if (e < hi) {
    const ushort4 v = *(const ushort4*)(hb + ((size_t)sg[e] << 8));
    a0 += bf2f(v.x); a1 += bf2f(v.y); a2 += bf2f(v.z); a3 += bf2f(v.w);
  }
  const float4 b = ((const float4*)bias)[lane];
  f32x4 o = {a0 + b.x, a1 + b.y, a2 + b.z, a3 + b.w};
  __builtin_nontemporal_store(o, (f32x4*)out + (size_t)wid * 64 + lane);
}

// ---------------- Tier B: round-2 path (per-relation gathered GEMM + atomics) ----------------

__global__ void k_init_out(float* __restrict__ out, const float* __restrict__ bias) {
  int i = blockIdx.x * blockDim.x + threadIdx.x;
  ((float4*)out)[i] = ((const float4*)bias)[i & 63];
}
__global__ void k_zero8(int* __restrict__ meta) {
  if (threadIdx.x < 8) meta[threadIdx.x] = 0;
}
#define SORT_BLOCKS 256
#define SORT_CHUNK ((EDGES + SORT_BLOCKS - 1) / SORT_BLOCKS)
__global__ void k_hist(const int* __restrict__ et, int* __restrict__ meta) {
  __shared__ int lh[NREL];
  if (threadIdx.x < NREL) lh[threadIdx.x] = 0;
  __syncthreads();
  const int lo = blockIdx.x * SORT_CHUNK, hi = min(EDGES, lo + SORT_CHUNK);
  for (int e = lo + threadIdx.x; e < hi; e += blockDim.x) atomicAdd(&lh[et[e]], 1);
  __syncthreads();
  if (threadIdx.x < NREL && lh[threadIdx.x]) atomicAdd(&meta[threadIdx.x], lh[threadIdx.x]);
}
__global__ void k_scan(int* __restrict__ meta) {
  if (threadIdx.x == 0) {
    int s = 0;
    for (int r = 0; r < NREL; ++r) { meta[8 + r] = s; meta[17 + r] = s; s += meta[r]; }
    meta[16] = s;
  }
}
__global__ void k_scatter(const int* __restrict__ et, int* __restrict__ meta,
                          int* __restrict__ perm) {
  __shared__ int lh[NREL];
  __shared__ int lc[NREL];
  if (threadIdx.x < NREL) lh[threadIdx.x] = 0;
  __syncthreads();
  const int lo = blockIdx.x * SORT_CHUNK, hi = min(EDGES, lo + SORT_CHUNK);
  for (int e = lo + threadIdx.x; e < hi; e += blockDim.x) atomicAdd(&lh[et[e]], 1);
  __syncthreads();
  if (threadIdx.x < NREL) {
    const int c = lh[threadIdx.x];
    lc[threadIdx.x] = c ? atomicAdd(&meta[17 + threadIdx.x], c) : 0;
  }
  __syncthreads();
  for (int e = lo + threadIdx.x; e < hi; e += blockDim.x) {
    const int p = atomicAdd(&lc[et[e]], 1);
    perm[p] = e;
  }
}
__global__ __launch_bounds__(256) void k_gemm_b(
    const u16* __restrict__ xb, const u16* __restrict__ wb,
    const int* __restrict__ perm, const int* __restrict__ meta,
    const int* __restrict__ esrc, const int* __restrict__ edst,
    float* __restrict__ out)
{
  const int r = blockIdx.z;
  const int estart = meta[8 + r], eend = meta[9 + r];
  const int base = estart + (int)blockIdx.x * 128;
  if (base >= eend) return;
  const int mcount = min(128, eend - base);
  const int ny = blockIdx.y;
  __shared__ int s_src[128];
  __shared__ int s_dst[128];
  __shared__ __align__(16) u16 s_a[128 * 32];
  __shared__ __align__(16) u16 s_b[128 * 32];
  const int tid = threadIdx.x;
  if (tid < 128) {
    int sv = 0, dv = 0;
    if (tid < mcount) { int e = perm[base + tid]; sv = esrc[e]; dv = edst[e]; }
    s_src[tid] = sv; s_dst[tid] = dv;
  }
  __syncthreads();
  const int lane = tid & 63;
  const int wv = tid >> 6;
  const int wr = wv >> 1, wc = wv & 1;
  const int swz = (lane & 3) ^ ((lane >> 2) & 3) ^ (lane >> 4);
  f32x4 acc[4][4];
#pragma unroll
  for (int m = 0; m < 4; ++m)
#pragma unroll
    for (int n = 0; n < 4; ++n) acc[m][n] = f32x4{0.f, 0.f, 0.f, 0.f};
  const int arow0 = wv * 32;
  const size_t wbase = ((size_t)r << 16) + ((size_t)ny << 15);
  for (int ks = 0; ks < 8; ++ks) {
#pragma unroll
    for (int c2 = 0; c2 < 2; ++c2) {
      const int rowb = arow0 + c2 * 16;
      const int row  = rowb + (lane >> 2);
      const u16* ga = xb + ((size_t)s_src[row] << 8) + (ks << 5) + (swz << 3);
      __builtin_amdgcn_global_load_lds((const GLOBAL_AS uint32_t*)ga,
                                       (LDS_AS uint32_t*)(s_a + rowb * 32), 16, 0, 0);
      const u16* gb = wb + wbase + ((size_t)row << 8) + (ks << 5) + (swz << 3);
      __builtin_amdgcn_global_load_lds((const GLOBAL_AS uint32_t*)gb,
                                       (LDS_AS uint32_t*)(s_b + rowb * 32), 16, 0, 0);
    }
    __syncthreads();
    bf16x8 af[4], bfr[4];
#pragma unroll
    for (int m = 0; m < 4; ++m)
      af[m] = *(const bf16x8*)(s_a + (wr * 64 + m * 16 + (lane & 15)) * 32 + swz * 8);
#pragma unroll
    for (int n = 0; n < 4; ++n)
      bfr[n] = *(const bf16x8*)(s_b + (wc * 64 + n * 16 + (lane & 15)) * 32 + swz * 8);
#pragma unroll
    for (int m = 0; m < 4; ++m)
#pragma unroll
      for (int n = 0; n < 4; ++n)
        acc[m][n] = __builtin_amdgcn_mfma_f32_16x16x32_bf16(af[m], bfr[n], acc[m][n], 0, 0, 0);
    __syncthreads();
  }
  const int colb = ny * 128 + wc * 64 + (lane & 15);
#pragma unroll
  for (int m = 0; m < 4; ++m) {
#pragma unroll
    for (int q = 0; q < 4; ++q) {
      const int rl = wr * 64 + m * 16 + (lane >> 4) * 4 + q;
      if (rl < mcount) {
        float* op = out + (size_t)s_dst[rl] * DIM + colb;
#pragma unroll
        for (int n = 0; n < 4; ++n) atomicAdd(op + n * 16, acc[m][n][q]);
      }
    }
  }
}

// Tier C: correctness-only fallback.
__global__ void k_naive(const float* __restrict__ x, const float* __restrict__ w,
                        const int* __restrict__ esrc, const int* __restrict__ edst,
                        const int* __restrict__ et, float* __restrict__ out)
{
  const int lane = threadIdx.x & 63;
  int gw = (blockIdx.x * blockDim.x + threadIdx.x) >> 6;
  const int nw = (gridDim.x * blockDim.x) >> 6;
  for (int e = gw; e < EDGES; e += nw) {
    const int s = esrc[e], d = edst[e], r = et[e];
    const float* xr = x + (size_t)s * DIM;
    const float* wr0 = w + (size_t)r * DIM * DIM;
    float a[4] = {0.f, 0.f, 0.f, 0.f};
    for (int i = 0; i < DIM; ++i) {
      const float xv = xr[i];
#pragma unroll
      for (int c = 0; c < 4; ++c) a[c] += xv * wr0[(size_t)(lane + c * 64) * DIM + i];
    }
#pragma unroll
    for (int c = 0; c < 4; ++c) atomicAdd(&out[(size_t)d * DIM + lane + c * 64], a[c]);
  }
}

extern "C" void kernel_launch(void* const* d_in, const int* in_sizes, int n_in,
                              void* d_out, int out_size, void* d_ws, size_t ws_size,
                              hipStream_t stream) {
  const float* x    = (const float*)d_in[0];
  const float* w    = (const float*)d_in[1];
  const float* bias = (const float*)d_in[2];
  const int* eidx   = (const int*)d_in[3];
  const int* et     = (const int*)d_in[4];
  const int* esrc = eidx;
  const int* edst = eidx + EDGES;
  float* out = (float*)d_out;

  auto pad = [](size_t v) { return (v + 255) & ~(size_t)255; };

  // Tier A layout
  size_t needA = 0;
  const size_t a_xb = needA;  needA = pad(needA + (size_t)NODES * DIM * 2);
  const size_t a_wb = needA;  needA = pad(needA + (size_t)NREL * DIM * DIM * 2);
  const size_t a_h  = needA;  needA = pad(needA + (size_t)NODES * NJ * 2);
  const size_t a_cnt = needA; needA = pad(needA + (size_t)NODES * 4);
  const size_t a_rp  = needA; needA = pad(needA + ((size_t)NODES + 1) * 4);
  const size_t a_cur = needA; needA = pad(needA + (size_t)NODES * 4);
  const size_t a_bs  = needA; needA = pad(needA + (size_t)SCAN_BLOCKS * 4);
  const size_t a_sg  = needA; needA = pad(needA + (size_t)EDGES * 4);

  // Tier B layout
  size_t needB = 0;
  const size_t b_xb = needB;   needB = pad(needB + (size_t)NODES * DIM * 2);
  const size_t b_wb = needB;   needB = pad(needB + (size_t)NREL * DIM * DIM * 2);
  const size_t b_perm = needB; needB = pad(needB + (size_t)EDGES * 4);
  const size_t b_meta = needB; needB = pad(needB + 64 * 4);

  char* ws = (char*)d_ws;
  if (needA <= ws_size) {
    u16* xb = (u16*)(ws + a_xb);
    u16* wb = (u16*)(ws + a_wb);
    u16* h  = (u16*)(ws + a_h);
    int* cnt = (int*)(ws + a_cnt);
    int* rp  = (int*)(ws + a_rp);
    int* cur = (int*)(ws + a_cur);
    int* bs  = (int*)(ws + a_bs);
    int* sg  = (int*)(ws + a_sg);

    k_cvt<<<12500, 256, 0, stream>>>(x, xb, NODES * DIM / 4);
    k_cvt<<<512, 256, 0, stream>>>(w, wb, NREL * DIM * DIM / 4);
    (void)hipMemsetAsync(cnt, 0, (size_t)NODES * 4, stream);
    k_hist2<<<3125, 256, 0, stream>>>(edst, cnt);
    k_bsum<<<SCAN_BLOCKS, 256, 0, stream>>>(cnt, bs);
    k_bscan<<<1, 256, 0, stream>>>(bs);
    k_scan2<<<SCAN_BLOCKS, 256, 0, stream>>>(cnt, bs, rp, cur);
    k_scatter2<<<3125, 256, 0, stream>>>(esrc, edst, et, cur, sg);
    k_gemm<<<392 * 16, 256, 0, stream>>>(xb, wb, h);
    k_reduce<<<(NODES * 64 + 255) / 256, 256, 0, stream>>>(h, rp, sg, bias, out);
  } else if (needB <= ws_size) {
    u16* xb  = (u16*)(ws + b_xb);
    u16* wbb = (u16*)(ws + b_wb);
    int* perm = (int*)(ws + b_perm);
    int* meta = (int*)(ws + b_meta);
    k_init_out<<<12500, 256, 0, stream>>>(out, bias);
    k_cvt<<<12500, 256, 0, stream>>>(x, xb, NODES * DIM / 4);
    k_cvt<<<512, 256, 0, stream>>>(w, wbb, NREL * DIM * DIM / 4);
    k_zero8<<<1, 64, 0, stream>>>(meta);
    k_hist<<<SORT_BLOCKS, 256, 0, stream>>>(et, meta);
    k_scan<<<1, 1, 0, stream>>>(meta);
    k_scatter<<<SORT_BLOCKS, 256, 0, stream>>>(et, meta, perm);
    dim3 g(6250, 2, NREL);
    k_gemm_b<<<g, 256, 0, stream>>>(xb, wbb, perm, meta, esrc, edst, out);
  } else {
    k_init_out<<<12500, 256, 0, stream>>>(out, bias);
    k_naive<<<2048, 256, 0, stream>>>(x, w, esrc, edst, et, out);
  }
}

// Round 7
// 268.412 us; speedup vs baseline: 1.4388x; 1.0155x over previous
//
#include <hip/hip_runtime.h>
#include <hip/hip_bf16.h>
#include <stdint.h>

#define NODES 50000
#define EDGES 800000
#define DIM 256
#define NREL 8
#define NJ (NREL * DIM)  // 2048 combined output cols (r*256+o)

typedef unsigned short u16;
typedef __attribute__((ext_vector_type(8))) __bf16 bf16x8;
typedef __attribute__((ext_vector_type(8))) unsigned short us8;
typedef __attribute__((ext_vector_type(4))) float f32x4;

#define GLOBAL_AS __attribute__((address_space(1)))
#define LDS_AS __attribute__((address_space(3)))

__device__ __forceinline__ u16 f2bf(float f) {
  uint32_t u = __builtin_bit_cast(uint32_t, f);
  u += 0x7FFFu + ((u >> 16) & 1u);  // RNE; inputs finite
  return (u16)(u >> 16);
}
__device__ __forceinline__ float bf2f(u16 u) {
  uint32_t t = (uint32_t)u << 16;
  return __builtin_bit_cast(float, t);
}

// Merged x+w bf16 conversion (one launch instead of two)
__global__ void k_cvt2(const float* __restrict__ x, const float* __restrict__ w,
                       u16* __restrict__ xb, u16* __restrict__ wb) {
  const int n4x = NODES * DIM / 4;       // 3,200,000
  const int n4w = NREL * DIM * DIM / 4;  // 131,072
  int i = blockIdx.x * blockDim.x + threadIdx.x;
  if (i < n4x) {
    float4 v = ((const float4*)x)[i];
    ushort4 o;
    o.x = f2bf(v.x); o.y = f2bf(v.y); o.z = f2bf(v.z); o.w = f2bf(v.w);
    ((ushort4*)xb)[i] = o;
  } else if (i < n4x + n4w) {
    const int j = i - n4x;
    float4 v = ((const float4*)w)[j];
    ushort4 o;
    o.x = f2bf(v.x); o.y = f2bf(v.y); o.z = f2bf(v.z); o.w = f2bf(v.w);
    ((ushort4*)wb)[j] = o;
  }
}

__global__ void k_cvt(const float* __restrict__ in, u16* __restrict__ outp, int n4) {
  int i = blockIdx.x * blockDim.x + threadIdx.x;
  if (i >= n4) return;
  float4 v = ((const float4*)in)[i];
  ushort4 o;
  o.x = f2bf(v.x); o.y = f2bf(v.y); o.z = f2bf(v.z); o.w = f2bf(v.w);
  ((ushort4*)outp)[i] = o;
}

// ---------------- Tier A: dense GEMM -> dst-sorted gather-reduce ----------------

// h[n][j] = sum_i xb[n][i] * wb[j][i].  392 m-tiles (8 XCD bands x 49) x 16 j-tiles.
// T1 XCD-chunked mapping (r6: FETCH 207->27MB). This round: T3-minimum 2-phase
// double-buffer (STAGE of ks+1 issued BEFORE compute of ks; one barrier/k-step —
// r6's STAGE->barrier->compute exposed full L2 latency every k-step, MfmaUtil 22%)
// + coalesced epilogue via XOR-swizzled LDS transpose (64 scalar u16 stores -> 8x16B).
__global__ __launch_bounds__(256) void k_gemm(
    const u16* __restrict__ xb, const u16* __restrict__ wb, u16* __restrict__ h)
{
  const int bid = blockIdx.x;
  const int xcd = bid & 7;
  const int idx = bid >> 3;          // 0..783
  const int jg  = idx / 392;         // 0,1
  const int r2  = idx - jg * 392;
  const int m   = xcd * 49 + (r2 >> 3);
  const int mbase = m * 128;
  if (mbase >= NODES) return;
  const int jbase = (jg * 8 + (r2 & 7)) * 128;

  // 32KB: [a0 | b0 | a1 | b1], each 4096 u16; reused as 128x128 transpose tile.
  __shared__ __align__(16) u16 smem[16384];

  const int tid = threadIdx.x;
  const int lane = tid & 63;
  const int wv = tid >> 6;
  const int wr = wv >> 1, wc = wv & 1;
  const int swz = (lane & 3) ^ ((lane >> 2) & 3) ^ (lane >> 4);  // 16B-chunk idx

  f32x4 acc[4][4];
#pragma unroll
  for (int mm = 0; mm < 4; ++mm)
#pragma unroll
    for (int n = 0; n < 4; ++n) acc[mm][n] = f32x4{0.f, 0.f, 0.f, 0.f};

  const int arow0 = wv * 32;  // this wave stages rows [arow0, arow0+32)

  auto STAGE = [&](int buf, int ks) {
    u16* sa = smem + buf * 8192;
    u16* sb = sa + 4096;
#pragma unroll
    for (int c2 = 0; c2 < 2; ++c2) {
      const int rowb = arow0 + c2 * 16;
      const int row  = rowb + (lane >> 2);
      const int ar = min(mbase + row, NODES - 1);  // clamp last tile
      const u16* ga = xb + ((size_t)ar << 8) + (ks << 5) + (swz << 3);
      __builtin_amdgcn_global_load_lds((const GLOBAL_AS uint32_t*)ga,
                                       (LDS_AS uint32_t*)(sa + rowb * 32), 16, 0, 0);
      const u16* gb = wb + ((size_t)(jbase + row) << 8) + (ks << 5) + (swz << 3);
      __builtin_amdgcn_global_load_lds((const GLOBAL_AS uint32_t*)gb,
                                       (LDS_AS uint32_t*)(sb + rowb * 32), 16, 0, 0);
    }
  };

  STAGE(0, 0);
  __syncthreads();  // drain prologue stage
  int cur = 0;
  for (int ks = 0; ks < 8; ++ks) {
    if (ks < 7) STAGE(cur ^ 1, ks + 1);  // issue next-tile loads BEFORE compute
    const u16* sa = smem + cur * 8192;
    const u16* sb = sa + 4096;
    bf16x8 af[4], bfr[4];
#pragma unroll
    for (int mm = 0; mm < 4; ++mm)
      af[mm] = *(const bf16x8*)(sa + (wr * 64 + mm * 16 + (lane & 15)) * 32 + swz * 8);
#pragma unroll
    for (int n = 0; n < 4; ++n)
      bfr[n] = *(const bf16x8*)(sb + (wc * 64 + n * 16 + (lane & 15)) * 32 + swz * 8);
#pragma unroll
    for (int mm = 0; mm < 4; ++mm)
#pragma unroll
      for (int n = 0; n < 4; ++n)
        acc[mm][n] = __builtin_amdgcn_mfma_f32_16x16x32_bf16(af[mm], bfr[n], acc[mm][n], 0, 0, 0);
    __syncthreads();  // one drain per k-step: next-tile loads had the compute phase to land
    cur ^= 1;
  }

  // Epilogue: acc -> LDS tile (XOR key makes the 4 simultaneous rows hit disjoint
  // bank quartets), then coalesced 16B nt stores. D layout: col=lane&15,
  // row=(lane>>4)*4+q (m89-verified).
  u16* tile = smem;  // 128x128 u16 = 32KB
#pragma unroll
  for (int mm = 0; mm < 4; ++mm) {
#pragma unroll
    for (int q = 0; q < 4; ++q) {
      const int rt = wr * 64 + mm * 16 + (lane >> 4) * 4 + q;
      const int key = ((rt >> 2) & 3) << 4;
#pragma unroll
      for (int n = 0; n < 4; ++n) {
        const int ct = wc * 64 + n * 16 + (lane & 15);
        tile[rt * 128 + (ct ^ key)] = f2bf(acc[mm][n][q]);
      }
    }
  }
  __syncthreads();
#pragma unroll
  for (int i = 0; i < 8; ++i) {
    const int c = tid + i * 256;
    const int row = c >> 4, chunk = c & 15;
    const int grow = mbase + row;
    if (grow < NODES) {
      const int key = ((row >> 2) & 3) << 4;
      const us8 v = *(const us8*)(tile + row * 128 + ((chunk * 8) ^ key));
      __builtin_nontemporal_store(v, (us8*)(h + (size_t)grow * NJ + jbase) + chunk);
    }
  }
}

// ---- counting sort by dst (50K bins). Scan = 3 small multi-block kernels
// (r5 lesson: single-block scan was 124us at 0.15% occupancy). ----
#define SCAN_BLOCKS 196  // ceil(50000/256)

__global__ void k_hist2(const int* __restrict__ edst, int* __restrict__ cnt) {
  int e = blockIdx.x * blockDim.x + threadIdx.x;
  if (e < EDGES) atomicAdd(&cnt[edst[e]], 1);
}
__global__ void k_bsum(const int* __restrict__ cnt, int* __restrict__ bs) {
  int i = blockIdx.x * blockDim.x + threadIdx.x;
  int v = (i < NODES) ? cnt[i] : 0;
#pragma unroll
  for (int o = 32; o; o >>= 1) v += __shfl_down(v, o);
  __shared__ int wsum[4];
  if ((threadIdx.x & 63) == 0) wsum[threadIdx.x >> 6] = v;
  __syncthreads();
  if (threadIdx.x == 0) bs[blockIdx.x] = wsum[0] + wsum[1] + wsum[2] + wsum[3];
}
__global__ void k_bscan(int* __restrict__ bs) {  // exclusive scan of SCAN_BLOCKS, 1 block
  __shared__ int tmp[SCAN_BLOCKS];
  int t = threadIdx.x;
  if (t < SCAN_BLOCKS) tmp[t] = bs[t];
  __syncthreads();
  if (t == 0) {
    int s = 0;
    for (int i = 0; i < SCAN_BLOCKS; ++i) { int c = tmp[i]; tmp[i] = s; s += c; }
  }
  __syncthreads();
  if (t < SCAN_BLOCKS) bs[t] = tmp[t];
}
__global__ void k_scan2(const int* __restrict__ cnt, const int* __restrict__ bs,
                        int* __restrict__ row_ptr, int* __restrict__ cur) {
  int t = threadIdx.x;
  int i = blockIdx.x * blockDim.x + t;
  int v = (i < NODES) ? cnt[i] : 0;
  __shared__ int tmp[256];
  tmp[t] = v;
  __syncthreads();
  for (int o = 1; o < 256; o <<= 1) {  // Hillis-Steele inclusive
    int u = (t >= o) ? tmp[t - o] : 0;
    __syncthreads();
    tmp[t] += u;
    __syncthreads();
  }
  int val = bs[blockIdx.x] + tmp[t] - v;  // exclusive
  if (i <= NODES) row_ptr[i] = val;       // row_ptr[NODES] lands on EDGES
  if (i < NODES) cur[i] = val;
}
__global__ void k_scatter2(const int* __restrict__ esrc, const int* __restrict__ edst,
                           const int* __restrict__ et, int* __restrict__ cur,
                           int* __restrict__ sg) {
  int e = blockIdx.x * blockDim.x + threadIdx.x;
  if (e < EDGES) {
    int p = atomicAdd(&cur[edst[e]], 1);  // in-bin order irrelevant (sum commutes)
    sg[p] = esrc[e] * NREL + et[e];       // h row index
  }
}

// One wave per dst node: gather ~deg(16) rows of h (512B each), f32-accumulate,
// +bias, single coalesced row write (nt). 8-deep gather unroll for MLP.
__global__ __launch_bounds__(256) void k_reduce(
    const u16* __restrict__ h, const int* __restrict__ row_ptr,
    const int* __restrict__ sg, const float* __restrict__ bias,
    float* __restrict__ out)
{
  const int wid = (int)((blockIdx.x * blockDim.x + threadIdx.x) >> 6);
  if (wid >= NODES) return;
  const int lane = threadIdx.x & 63;
  const int lo = row_ptr[wid], hi = row_ptr[wid + 1];
  const u16* hb = h + lane * 4;

  float a0 = 0.f, a1 = 0.f, a2 = 0.f, a3 = 0.f;
  int e = lo;
  for (; e + 8 <= hi; e += 8) {  // 8 independent 512B gathers in flight
    const ushort4 v0 = *(const ushort4*)(hb + ((size_t)sg[e] << 8));
    const ushort4 v1 = *(const ushort4*)(hb + ((size_t)sg[e + 1] << 8));
    const ushort4 v2 = *(const ushort4*)(hb + ((size_t)sg[e + 2] << 8));
    const ushort4 v3 = *(const ushort4*)(hb + ((size_t)sg[e + 3] << 8));
    const ushort4 v4 = *(const ushort4*)(hb + ((size_t)sg[e + 4] << 8));
    const ushort4 v5 = *(const ushort4*)(hb + ((size_t)sg[e + 5] << 8));
    const ushort4 v6 = *(const ushort4*)(hb + ((size_t)sg[e + 6] << 8));
    const ushort4 v7 = *(const ushort4*)(hb + ((size_t)sg[e + 7] << 8));
    a0 += ((bf2f(v0.x) + bf2f(v1.x)) + (bf2f(v2.x) + bf2f(v3.x))) +
          ((bf2f(v4.x) + bf2f(v5.x)) + (bf2f(v6.x) + bf2f(v7.x)));
    a1 += ((bf2f(v0.y) + bf2f(v1.y)) + (bf2f(v2.y) + bf2f(v3.y))) +
          ((bf2f(v4.y) + bf2f(v5.y)) + (bf2f(v6.y) + bf2f(v7.y)));
    a2 += ((bf2f(v0.z) + bf2f(v1.z)) + (bf2f(v2.z) + bf2f(v3.z))) +
          ((bf2f(v4.z) + bf2f(v5.z)) + (bf2f(v6.z) + bf2f(v7.z)));
    a3 += ((bf2f(v0.w) + bf2f(v1.w)) + (bf2f(v2.w) + bf2f(v3.w))) +
          ((bf2f(v4.w) + bf2f(v5.w)) + (bf2f(v6.w) + bf2f(v7.w)));
  }
  for (; e + 2 <= hi; e += 2) {
    const ushort4 v0 = *(const ushort4*)(hb + ((size_t)sg[e] << 8));
    const ushort4 v1 = *(const ushort4*)(hb + ((size_t)sg[e + 1] << 8));
    a0 += bf2f(v0.x) + bf2f(v1.x);
    a1 += bf2f(v0.y) + bf2f(v1.y);
    a2 += bf2f(v0.z) + bf2f(v1.z);
    a3 += bf2f(v0.w) + bf2f(v1.w);
  }
  if (e < hi) {
    const ushort4 v = *(const ushort4*)(hb + ((size_t)sg[e] << 8));
    a0 += bf2f(v.x); a1 += bf2f(v.y); a2 += bf2f(v.z); a3 += bf2f(v.w);
  }
  const float4 b = ((const float4*)bias)[lane];
  f32x4 o = {a0 + b.x, a1 + b.y, a2 + b.z, a3 + b.w};
  __builtin_nontemporal_store(o, (f32x4*)out + (size_t)wid * 64 + lane);
}

// ---------------- Tier B: round-2 path (per-relation gathered GEMM + atomics) ----------------

__global__ void k_init_out(float* __restrict__ out, const float* __restrict__ bias) {
  int i = blockIdx.x * blockDim.x + threadIdx.x;
  ((float4*)out)[i] = ((const float4*)bias)[i & 63];
}
__global__ void k_zero8(int* __restrict__ meta) {
  if (threadIdx.x < 8) meta[threadIdx.x] = 0;
}
#define SORT_BLOCKS 256
#define SORT_CHUNK ((EDGES + SORT_BLOCKS - 1) / SORT_BLOCKS)
__global__ void k_hist(const int* __restrict__ et, int* __restrict__ meta) {
  __shared__ int lh[NREL];
  if (threadIdx.x < NREL) lh[threadIdx.x] = 0;
  __syncthreads();
  const int lo = blockIdx.x * SORT_CHUNK, hi = min(EDGES, lo + SORT_CHUNK);
  for (int e = lo + threadIdx.x; e < hi; e += blockDim.x) atomicAdd(&lh[et[e]], 1);
  __syncthreads();
  if (threadIdx.x < NREL && lh[threadIdx.x]) atomicAdd(&meta[threadIdx.x], lh[threadIdx.x]);
}
__global__ void k_scan(int* __restrict__ meta) {
  if (threadIdx.x == 0) {
    int s = 0;
    for (int r = 0; r < NREL; ++r) { meta[8 + r] = s; meta[17 + r] = s; s += meta[r]; }
    meta[16] = s;
  }
}
__global__ void k_scatter(const int* __restrict__ et, int* __restrict__ meta,
                          int* __restrict__ perm) {
  __shared__ int lh[NREL];
  __shared__ int lc[NREL];
  if (threadIdx.x < NREL) lh[threadIdx.x] = 0;
  __syncthreads();
  const int lo = blockIdx.x * SORT_CHUNK, hi = min(EDGES, lo + SORT_CHUNK);
  for (int e = lo + threadIdx.x; e < hi; e += blockDim.x) atomicAdd(&lh[et[e]], 1);
  __syncthreads();
  if (threadIdx.x < NREL) {
    const int c = lh[threadIdx.x];
    lc[threadIdx.x] = c ? atomicAdd(&meta[17 + threadIdx.x], c) : 0;
  }
  __syncthreads();
  for (int e = lo + threadIdx.x; e < hi; e += blockDim.x) {
    const int p = atomicAdd(&lc[et[e]], 1);
    perm[p] = e;
  }
}
__global__ __launch_bounds__(256) void k_gemm_b(
    const u16* __restrict__ xb, const u16* __restrict__ wb,
    const int* __restrict__ perm, const int* __restrict__ meta,
    const int* __restrict__ esrc, const int* __restrict__ edst,
    float* __restrict__ out)
{
  const int r = blockIdx.z;
  const int estart = meta[8 + r], eend = meta[9 + r];
  const int base = estart + (int)blockIdx.x * 128;
  if (base >= eend) return;
  const int mcount = min(128, eend - base);
  const int ny = blockIdx.y;
  __shared__ int s_src[128];
  __shared__ int s_dst[128];
  __shared__ __align__(16) u16 s_a[128 * 32];
  __shared__ __align__(16) u16 s_b[128 * 32];
  const int tid = threadIdx.x;
  if (tid < 128) {
    int sv = 0, dv = 0;
    if (tid < mcount) { int e = perm[base + tid]; sv = esrc[e]; dv = edst[e]; }
    s_src[tid] = sv; s_dst[tid] = dv;
  }
  __syncthreads();
  const int lane = tid & 63;
  const int wv = tid >> 6;
  const int wr = wv >> 1, wc = wv & 1;
  const int swz = (lane & 3) ^ ((lane >> 2) & 3) ^ (lane >> 4);
  f32x4 acc[4][4];
#pragma unroll
  for (int m = 0; m < 4; ++m)
#pragma unroll
    for (int n = 0; n < 4; ++n) acc[m][n] = f32x4{0.f, 0.f, 0.f, 0.f};
  const int arow0 = wv * 32;
  const size_t wbase = ((size_t)r << 16) + ((size_t)ny << 15);
  for (int ks = 0; ks < 8; ++ks) {
#pragma unroll
    for (int c2 = 0; c2 < 2; ++c2) {
      const int rowb = arow0 + c2 * 16;
      const int row  = rowb + (lane >> 2);
      const u16* ga = xb + ((size_t)s_src[row] << 8) + (ks << 5) + (swz << 3);
      __builtin_amdgcn_global_load_lds((const GLOBAL_AS uint32_t*)ga,
                                       (LDS_AS uint32_t*)(s_a + rowb * 32), 16, 0, 0);
      const u16* gb = wb + wbase + ((size_t)row << 8) + (ks << 5) + (swz << 3);
      __builtin_amdgcn_global_load_lds((const GLOBAL_AS uint32_t*)gb,
                                       (LDS_AS uint32_t*)(s_b + rowb * 32), 16, 0, 0);
    }
    __syncthreads();
    bf16x8 af[4], bfr[4];
#pragma unroll
    for (int m = 0; m < 4; ++m)
      af[m] = *(const bf16x8*)(s_a + (wr * 64 + m * 16 + (lane & 15)) * 32 + swz * 8);
#pragma unroll
    for (int n = 0; n < 4; ++n)
      bfr[n] = *(const bf16x8*)(s_b + (wc * 64 + n * 16 + (lane & 15)) * 32 + swz * 8);
#pragma unroll
    for (int m = 0; m < 4; ++m)
#pragma unroll
      for (int n = 0; n < 4; ++n)
        acc[m][n] = __builtin_amdgcn_mfma_f32_16x16x32_bf16(af[m], bfr[n], acc[m][n], 0, 0, 0);
    __syncthreads();
  }
  const int colb = ny * 128 + wc * 64 + (lane & 15);
#pragma unroll
  for (int m = 0; m < 4; ++m) {
#pragma unroll
    for (int q = 0; q < 4; ++q) {
      const int rl = wr * 64 + m * 16 + (lane >> 4) * 4 + q;
      if (rl < mcount) {
        float* op = out + (size_t)s_dst[rl] * DIM + colb;
#pragma unroll
        for (int n = 0; n < 4; ++n) atomicAdd(op + n * 16, acc[m][n][q]);
      }
    }
  }
}

// Tier C: correctness-only fallback.
__global__ void k_naive(const float* __restrict__ x, const float* __restrict__ w,
                        const int* __restrict__ esrc, const int* __restrict__ edst,
                        const int* __restrict__ et, float* __restrict__ out)
{
  const int lane = threadIdx.x & 63;
  int gw = (blockIdx.x * blockDim.x + threadIdx.x) >> 6;
  const int nw = (gridDim.x * blockDim.x) >> 6;
  for (int e = gw; e < EDGES; e += nw) {
    const int s = esrc[e], d = edst[e], r = et[e];
    const float* xr = x + (size_t)s * DIM;
    const float* wr0 = w + (size_t)r * DIM * DIM;
    float a[4] = {0.f, 0.f, 0.f, 0.f};
    for (int i = 0; i < DIM; ++i) {
      const float xv = xr[i];
#pragma unroll
      for (int c = 0; c < 4; ++c) a[c] += xv * wr0[(size_t)(lane + c * 64) * DIM + i];
    }
#pragma unroll
    for (int c = 0; c < 4; ++c) atomicAdd(&out[(size_t)d * DIM + lane + c * 64], a[c]);
  }
}

extern "C" void kernel_launch(void* const* d_in, const int* in_sizes, int n_in,
                              void* d_out, int out_size, void* d_ws, size_t ws_size,
                              hipStream_t stream) {
  const float* x    = (const float*)d_in[0];
  const float* w    = (const float*)d_in[1];
  const float* bias = (const float*)d_in[2];
  const int* eidx   = (const int*)d_in[3];
  const int* et     = (const int*)d_in[4];
  const int* esrc = eidx;
  const int* edst = eidx + EDGES;
  float* out = (float*)d_out;

  auto pad = [](size_t v) { return (v + 255) & ~(size_t)255; };

  // Tier A layout
  size_t needA = 0;
  const size_t a_xb = needA;  needA = pad(needA + (size_t)NODES * DIM * 2);
  const size_t a_wb = needA;  needA = pad(needA + (size_t)NREL * DIM * DIM * 2);
  const size_t a_h  = needA;  needA = pad(needA + (size_t)NODES * NJ * 2);
  const size_t a_cnt = needA; needA = pad(needA + (size_t)NODES * 4);
  const size_t a_rp  = needA; needA = pad(needA + ((size_t)NODES + 1) * 4);
  const size_t a_cur = needA; needA = pad(needA + (size_t)NODES * 4);
  const size_t a_bs  = needA; needA = pad(needA + (size_t)SCAN_BLOCKS * 4);
  const size_t a_sg  = needA; needA = pad(needA + (size_t)EDGES * 4);

  // Tier B layout
  size_t needB = 0;
  const size_t b_xb = needB;   needB = pad(needB + (size_t)NODES * DIM * 2);
  const size_t b_wb = needB;   needB = pad(needB + (size_t)NREL * DIM * DIM * 2);
  const size_t b_perm = needB; needB = pad(needB + (size_t)EDGES * 4);
  const size_t b_meta = needB; needB = pad(needB + 64 * 4);

  char* ws = (char*)d_ws;
  if (needA <= ws_size) {
    u16* xb = (u16*)(ws + a_xb);
    u16* wb = (u16*)(ws + a_wb);
    u16* h  = (u16*)(ws + a_h);
    int* cnt = (int*)(ws + a_cnt);
    int* rp  = (int*)(ws + a_rp);
    int* cur = (int*)(ws + a_cur);
    int* bs  = (int*)(ws + a_bs);
    int* sg  = (int*)(ws + a_sg);

    const int n4 = NODES * DIM / 4 + NREL * DIM * DIM / 4;
    k_cvt2<<<(n4 + 255) / 256, 256, 0, stream>>>(x, w, xb, wb);
    (void)hipMemsetAsync(cnt, 0, (size_t)NODES * 4, stream);
    k_hist2<<<3125, 256, 0, stream>>>(edst, cnt);
    k_bsum<<<SCAN_BLOCKS, 256, 0, stream>>>(cnt, bs);
    k_bscan<<<1, 256, 0, stream>>>(bs);
    k_scan2<<<SCAN_BLOCKS, 256, 0, stream>>>(cnt, bs, rp, cur);
    k_scatter2<<<3125, 256, 0, stream>>>(esrc, edst, et, cur, sg);
    k_gemm<<<392 * 16, 256, 0, stream>>>(xb, wb, h);
    k_reduce<<<(NODES * 64 + 255) / 256, 256, 0, stream>>>(h, rp, sg, bias, out);
  } else if (needB <= ws_size) {
    u16* xb  = (u16*)(ws + b_xb);
    u16* wbb = (u16*)(ws + b_wb);
    int* perm = (int*)(ws + b_perm);
    int* meta = (int*)(ws + b_meta);
    k_init_out<<<12500, 256, 0, stream>>>(out, bias);
    k_cvt<<<12500, 256, 0, stream>>>(x, xb, NODES * DIM / 4);
    k_cvt<<<512, 256, 0, stream>>>(w, wbb, NREL * DIM * DIM / 4);
    k_zero8<<<1, 64, 0, stream>>>(meta);
    k_hist<<<SORT_BLOCKS, 256, 0, stream>>>(et, meta);
    k_scan<<<1, 1, 0, stream>>>(meta);
    k_scatter<<<SORT_BLOCKS, 256, 0, stream>>>(et, meta, perm);
    dim3 g(6250, 2, NREL);
    k_gemm_b<<<g, 256, 0, stream>>>(xb, wbb, perm, meta, esrc, edst, out);
  } else {
    k_init_out<<<12500, 256, 0, stream>>>(out, bias);
    k_naive<<<2048, 256, 0, stream>>>(x, w, esrc, edst, et, out);
  }
}

// Round 8
// 250.109 us; speedup vs baseline: 1.5441x; 1.0732x over previous
//
#include <hip/hip_runtime.h>
#include <hip/hip_bf16.h>
#include <stdint.h>

#define NODES 50000
#define EDGES 800000
#define DIM 256
#define NREL 8
#define NJ (NREL * DIM)  // 2048 combined output cols (r*256+o)

typedef unsigned short u16;
typedef __attribute__((ext_vector_type(8))) __bf16 bf16x8;
typedef __attribute__((ext_vector_type(8))) unsigned short us8;
typedef __attribute__((ext_vector_type(4))) float f32x4;

#define GLOBAL_AS __attribute__((address_space(1)))
#define LDS_AS __attribute__((address_space(3)))

__device__ __forceinline__ u16 f2bf(float f) {
  uint32_t u = __builtin_bit_cast(uint32_t, f);
  u += 0x7FFFu + ((u >> 16) & 1u);  // RNE; inputs finite
  return (u16)(u >> 16);
}
__device__ __forceinline__ float bf2f(u16 u) {
  uint32_t t = (uint32_t)u << 16;
  return __builtin_bit_cast(float, t);
}

// Merged x+w bf16 conversion (one launch instead of two)
__global__ void k_cvt2(const float* __restrict__ x, const float* __restrict__ w,
                       u16* __restrict__ xb, u16* __restrict__ wb) {
  const int n4x = NODES * DIM / 4;       // 3,200,000
  const int n4w = NREL * DIM * DIM / 4;  // 131,072
  int i = blockIdx.x * blockDim.x + threadIdx.x;
  if (i < n4x) {
    float4 v = ((const float4*)x)[i];
    ushort4 o;
    o.x = f2bf(v.x); o.y = f2bf(v.y); o.z = f2bf(v.z); o.w = f2bf(v.w);
    ((ushort4*)xb)[i] = o;
  } else if (i < n4x + n4w) {
    const int j = i - n4x;
    float4 v = ((const float4*)w)[j];
    ushort4 o;
    o.x = f2bf(v.x); o.y = f2bf(v.y); o.z = f2bf(v.z); o.w = f2bf(v.w);
    ((ushort4*)wb)[j] = o;
  }
}

__global__ void k_cvt(const float* __restrict__ in, u16* __restrict__ outp, int n4) {
  int i = blockIdx.x * blockDim.x + threadIdx.x;
  if (i >= n4) return;
  float4 v = ((const float4*)in)[i];
  ushort4 o;
  o.x = f2bf(v.x); o.y = f2bf(v.y); o.z = f2bf(v.z); o.w = f2bf(v.w);
  ((ushort4*)outp)[i] = o;
}

// ---------------- Tier A: dense GEMM -> dst-sorted gather-reduce ----------------

// h[n][j] = sum_i xb[n][i] * wb[j][i].  392 m-tiles (8 XCD bands x 49) x 16 j-tiles.
// T1 XCD mapping (r6: FETCH 207->27MB).  This round: T4 counted-vmcnt pipeline —
// r7's __syncthreads() drained vmcnt(0) including the just-issued next-tile loads,
// exposing residual L2 latency every k-step (MfmaUtil 25%).  Now: 3 LDS buffers,
// stage(ks+1) -> s_waitcnt vmcnt(4) (prev stage done, new stage in flight) ->
// raw s_barrier -> ds_read/MFMA.  One barrier per k-step, loads never drained to 0.
// 3 buffers needed: with 2, stage(ks+2) (issued pre-barrier) races a slow wave's
// ds_read(ks) of the same buffer.  Safety: write to buf b is issued only after
// barrier(ks-1); all reads of b (iter ks-2) complete before any wave passes
// barrier(ks-1), since the consuming MFMA's lgkmcnt-wait precedes it.
__global__ __launch_bounds__(256) void k_gemm(
    const u16* __restrict__ xb, const u16* __restrict__ wb, u16* __restrict__ h)
{
  const int bid = blockIdx.x;
  const int xcd = bid & 7;
  const int idx = bid >> 3;          // 0..783
  const int jg  = idx / 392;         // 0,1
  const int r2  = idx - jg * 392;
  const int m   = xcd * 49 + (r2 >> 3);
  const int mbase = m * 128;
  if (mbase >= NODES) return;
  const int jbase = (jg * 8 + (r2 & 7)) * 128;

  // 48KB: 3 x [A 4096 | B 4096] u16; first 32KB reused as 128x128 epilogue tile.
  __shared__ __align__(16) u16 smem[24576];

  const int tid = threadIdx.x;
  const int lane = tid & 63;
  const int wv = tid >> 6;
  const int wr = wv >> 1, wc = wv & 1;
  const int swz = (lane & 3) ^ ((lane >> 2) & 3) ^ (lane >> 4);  // 16B-chunk idx

  f32x4 acc[4][4];
#pragma unroll
  for (int mm = 0; mm < 4; ++mm)
#pragma unroll
    for (int n = 0; n < 4; ++n) acc[mm][n] = f32x4{0.f, 0.f, 0.f, 0.f};

  const int arow0 = wv * 32;  // this wave stages rows [arow0, arow0+32)

  auto STAGE = [&](int buf, int ks) {
    u16* sa = smem + buf * 8192;
    u16* sb = sa + 4096;
#pragma unroll
    for (int c2 = 0; c2 < 2; ++c2) {
      const int rowb = arow0 + c2 * 16;
      const int row  = rowb + (lane >> 2);
      const int ar = min(mbase + row, NODES - 1);  // clamp last tile
      const u16* ga = xb + ((size_t)ar << 8) + (ks << 5) + (swz << 3);
      __builtin_amdgcn_global_load_lds((const GLOBAL_AS uint32_t*)ga,
                                       (LDS_AS uint32_t*)(sa + rowb * 32), 16, 0, 0);
      const u16* gb = wb + ((size_t)(jbase + row) << 8) + (ks << 5) + (swz << 3);
      __builtin_amdgcn_global_load_lds((const GLOBAL_AS uint32_t*)gb,
                                       (LDS_AS uint32_t*)(sb + rowb * 32), 16, 0, 0);
    }
  };

  STAGE(0, 0);  // 4 loads in flight
#pragma unroll
  for (int ks = 0; ks < 8; ++ks) {
    if (ks < 7) {
      STAGE((ks + 1) % 3, ks + 1);                       // +4 loads (8 in flight)
      asm volatile("s_waitcnt vmcnt(4)" ::: "memory");   // prev stage landed
    } else {
      asm volatile("s_waitcnt vmcnt(0)" ::: "memory");   // final stage landed
    }
    __builtin_amdgcn_s_barrier();                        // no vmcnt(0) drain here

    const u16* sa = smem + (ks % 3) * 8192;
    const u16* sb = sa + 4096;
    bf16x8 af[4], bfr[4];
#pragma unroll
    for (int mm = 0; mm < 4; ++mm)
      af[mm] = *(const bf16x8*)(sa + (wr * 64 + mm * 16 + (lane & 15)) * 32 + swz * 8);
#pragma unroll
    for (int n = 0; n < 4; ++n)
      bfr[n] = *(const bf16x8*)(sb + (wc * 64 + n * 16 + (lane & 15)) * 32 + swz * 8);
#pragma unroll
    for (int mm = 0; mm < 4; ++mm)
#pragma unroll
      for (int n = 0; n < 4; ++n)
        acc[mm][n] = __builtin_amdgcn_mfma_f32_16x16x32_bf16(af[mm], bfr[n], acc[mm][n], 0, 0, 0);
  }
  __syncthreads();  // all waves done reading bufs before tile overwrite

  // Epilogue: acc -> LDS tile (XOR key: 4 simultaneous rows hit disjoint bank
  // quartets), then coalesced 16B stores.  Plain stores this round (nt removed):
  // if L3 is allocate-on-write, k_reduce's 410MB of h gathers become L3 hits.
  u16* tile = smem;  // 128x128 u16 = 32KB
#pragma unroll
  for (int mm = 0; mm < 4; ++mm) {
#pragma unroll
    for (int q = 0; q < 4; ++q) {
      const int rt = wr * 64 + mm * 16 + (lane >> 4) * 4 + q;
      const int key = ((rt >> 2) & 3) << 4;
#pragma unroll
      for (int n = 0; n < 4; ++n) {
        const int ct = wc * 64 + n * 16 + (lane & 15);
        tile[rt * 128 + (ct ^ key)] = f2bf(acc[mm][n][q]);
      }
    }
  }
  __syncthreads();
#pragma unroll
  for (int i = 0; i < 8; ++i) {
    const int c = tid + i * 256;
    const int row = c >> 4, chunk = c & 15;
    const int grow = mbase + row;
    if (grow < NODES) {
      const int key = ((row >> 2) & 3) << 4;
      const us8 v = *(const us8*)(tile + row * 128 + ((chunk * 8) ^ key));
      *((us8*)(h + (size_t)grow * NJ + jbase) + chunk) = v;
    }
  }
}

// ---- counting sort by dst (50K bins). Scan = 3 small multi-block kernels
// (r5 lesson: single-block scan was 124us at 0.15% occupancy). ----
#define SCAN_BLOCKS 196  // ceil(50000/256)

__global__ void k_hist2(const int* __restrict__ edst, int* __restrict__ cnt) {
  int e = blockIdx.x * blockDim.x + threadIdx.x;
  if (e < EDGES) atomicAdd(&cnt[edst[e]], 1);
}
__global__ void k_bsum(const int* __restrict__ cnt, int* __restrict__ bs) {
  int i = blockIdx.x * blockDim.x + threadIdx.x;
  int v = (i < NODES) ? cnt[i] : 0;
#pragma unroll
  for (int o = 32; o; o >>= 1) v += __shfl_down(v, o);
  __shared__ int wsum[4];
  if ((threadIdx.x & 63) == 0) wsum[threadIdx.x >> 6] = v;
  __syncthreads();
  if (threadIdx.x == 0) bs[blockIdx.x] = wsum[0] + wsum[1] + wsum[2] + wsum[3];
}
__global__ void k_bscan(int* __restrict__ bs) {  // exclusive scan of SCAN_BLOCKS, 1 block
  __shared__ int tmp[SCAN_BLOCKS];
  int t = threadIdx.x;
  if (t < SCAN_BLOCKS) tmp[t] = bs[t];
  __syncthreads();
  if (t == 0) {
    int s = 0;
    for (int i = 0; i < SCAN_BLOCKS; ++i) { int c = tmp[i]; tmp[i] = s; s += c; }
  }
  __syncthreads();
  if (t < SCAN_BLOCKS) bs[t] = tmp[t];
}
__global__ void k_scan2(const int* __restrict__ cnt, const int* __restrict__ bs,
                        int* __restrict__ row_ptr, int* __restrict__ cur) {
  int t = threadIdx.x;
  int i = blockIdx.x * blockDim.x + t;
  int v = (i < NODES) ? cnt[i] : 0;
  __shared__ int tmp[256];
  tmp[t] = v;
  __syncthreads();
  for (int o = 1; o < 256; o <<= 1) {  // Hillis-Steele inclusive
    int u = (t >= o) ? tmp[t - o] : 0;
    __syncthreads();
    tmp[t] += u;
    __syncthreads();
  }
  int val = bs[blockIdx.x] + tmp[t] - v;  // exclusive
  if (i <= NODES) row_ptr[i] = val;       // row_ptr[NODES] lands on EDGES
  if (i < NODES) cur[i] = val;
}
__global__ void k_scatter2(const int* __restrict__ esrc, const int* __restrict__ edst,
                           const int* __restrict__ et, int* __restrict__ cur,
                           int* __restrict__ sg) {
  int e = blockIdx.x * blockDim.x + threadIdx.x;
  if (e < EDGES) {
    int p = atomicAdd(&cur[edst[e]], 1);  // in-bin order irrelevant (sum commutes)
    sg[p] = esrc[e] * NREL + et[e];       // h row index
  }
}

// One wave per dst node: gather ~deg(16) rows of h (512B each), f32-accumulate,
// +bias, single coalesced row write (nt). 8-deep gather unroll for MLP.
__global__ __launch_bounds__(256) void k_reduce(
    const u16* __restrict__ h, const int* __restrict__ row_ptr,
    const int* __restrict__ sg, const float* __restrict__ bias,
    float* __restrict__ out)
{
  const int wid = (int)((blockIdx.x * blockDim.x + threadIdx.x) >> 6);
  if (wid >= NODES) return;
  const int lane = threadIdx.x & 63;
  const int lo = row_ptr[wid], hi = row_ptr[wid + 1];
  const u16* hb = h + lane * 4;

  float a0 = 0.f, a1 = 0.f, a2 = 0.f, a3 = 0.f;
  int e = lo;
  for (; e + 8 <= hi; e += 8) {  // 8 independent 512B gathers in flight
    const ushort4 v0 = *(const ushort4*)(hb + ((size_t)sg[e] << 8));
    const ushort4 v1 = *(const ushort4*)(hb + ((size_t)sg[e + 1] << 8));
    const ushort4 v2 = *(const ushort4*)(hb + ((size_t)sg[e + 2] << 8));
    const ushort4 v3 = *(const ushort4*)(hb + ((size_t)sg[e + 3] << 8));
    const ushort4 v4 = *(const ushort4*)(hb + ((size_t)sg[e + 4] << 8));
    const ushort4 v5 = *(const ushort4*)(hb + ((size_t)sg[e + 5] << 8));
    const ushort4 v6 = *(const ushort4*)(hb + ((size_t)sg[e + 6] << 8));
    const ushort4 v7 = *(const ushort4*)(hb + ((size_t)sg[e + 7] << 8));
    a0 += ((bf2f(v0.x) + bf2f(v1.x)) + (bf2f(v2.x) + bf2f(v3.x))) +
          ((bf2f(v4.x) + bf2f(v5.x)) + (bf2f(v6.x) + bf2f(v7.x)));
    a1 += ((bf2f(v0.y) + bf2f(v1.y)) + (bf2f(v2.y) + bf2f(v3.y))) +
          ((bf2f(v4.y) + bf2f(v5.y)) + (bf2f(v6.y) + bf2f(v7.y)));
    a2 += ((bf2f(v0.z) + bf2f(v1.z)) + (bf2f(v2.z) + bf2f(v3.z))) +
          ((bf2f(v4.z) + bf2f(v5.z)) + (bf2f(v6.z) + bf2f(v7.z)));
    a3 += ((bf2f(v0.w) + bf2f(v1.w)) + (bf2f(v2.w) + bf2f(v3.w))) +
          ((bf2f(v4.w) + bf2f(v5.w)) + (bf2f(v6.w) + bf2f(v7.w)));
  }
  for (; e + 2 <= hi; e += 2) {
    const ushort4 v0 = *(const ushort4*)(hb + ((size_t)sg[e] << 8));
    const ushort4 v1 = *(const ushort4*)(hb + ((size_t)sg[e + 1] << 8));
    a0 += bf2f(v0.x) + bf2f(v1.x);
    a1 += bf2f(v0.y) + bf2f(v1.y);
    a2 += bf2f(v0.z) + bf2f(v1.z);
    a3 += bf2f(v0.w) + bf2f(v1.w);
  }
  if (e < hi) {
    const ushort4 v = *(const ushort4*)(hb + ((size_t)sg[e] << 8));
    a0 += bf2f(v.x); a1 += bf2f(v.y); a2 += bf2f(v.z); a3 += bf2f(v.w);
  }
  const float4 b = ((const float4*)bias)[lane];
  f32x4 o = {a0 + b.x, a1 + b.y, a2 + b.z, a3 + b.w};
  __builtin_nontemporal_store(o, (f32x4*)out + (size_t)wid * 64 + lane);
}

// ---------------- Tier B: round-2 path (per-relation gathered GEMM + atomics) ----------------

__global__ void k_init_out(float* __restrict__ out, const float* __restrict__ bias) {
  int i = blockIdx.x * blockDim.x + threadIdx.x;
  ((float4*)out)[i] = ((const float4*)bias)[i & 63];
}
__global__ void k_zero8(int* __restrict__ meta) {
  if (threadIdx.x < 8) meta[threadIdx.x] = 0;
}
#define SORT_BLOCKS 256
#define SORT_CHUNK ((EDGES + SORT_BLOCKS - 1) / SORT_BLOCKS)
__global__ void k_hist(const int* __restrict__ et, int* __restrict__ meta) {
  __shared__ int lh[NREL];
  if (threadIdx.x < NREL) lh[threadIdx.x] = 0;
  __syncthreads();
  const int lo = blockIdx.x * SORT_CHUNK, hi = min(EDGES, lo + SORT_CHUNK);
  for (int e = lo + threadIdx.x; e < hi; e += blockDim.x) atomicAdd(&lh[et[e]], 1);
  __syncthreads();
  if (threadIdx.x < NREL && lh[threadIdx.x]) atomicAdd(&meta[threadIdx.x], lh[threadIdx.x]);
}
__global__ void k_scan(int* __restrict__ meta) {
  if (threadIdx.x == 0) {
    int s = 0;
    for (int r = 0; r < NREL; ++r) { meta[8 + r] = s; meta[17 + r] = s; s += meta[r]; }
    meta[16] = s;
  }
}
__global__ void k_scatter(const int* __restrict__ et, int* __restrict__ meta,
                          int* __restrict__ perm) {
  __shared__ int lh[NREL];
  __shared__ int lc[NREL];
  if (threadIdx.x < NREL) lh[threadIdx.x] = 0;
  __syncthreads();
  const int lo = blockIdx.x * SORT_CHUNK, hi = min(EDGES, lo + SORT_CHUNK);
  for (int e = lo + threadIdx.x; e < hi; e += blockDim.x) atomicAdd(&lh[et[e]], 1);
  __syncthreads();
  if (threadIdx.x < NREL) {
    const int c = lh[threadIdx.x];
    lc[threadIdx.x] = c ? atomicAdd(&meta[17 + threadIdx.x], c) : 0;
  }
  __syncthreads();
  for (int e = lo + threadIdx.x; e < hi; e += blockDim.x) {
    const int p = atomicAdd(&lc[et[e]], 1);
    perm[p] = e;
  }
}
__global__ __launch_bounds__(256) void k_gemm_b(
    const u16* __restrict__ xb, const u16* __restrict__ wb,
    const int* __restrict__ perm, const int* __restrict__ meta,
    const int* __restrict__ esrc, const int* __restrict__ edst,
    float* __restrict__ out)
{
  const int r = blockIdx.z;
  const int estart = meta[8 + r], eend = meta[9 + r];
  const int base = estart + (int)blockIdx.x * 128;
  if (base >= eend) return;
  const int mcount = min(128, eend - base);
  const int ny = blockIdx.y;
  __shared__ int s_src[128];
  __shared__ int s_dst[128];
  __shared__ __align__(16) u16 s_a[128 * 32];
  __shared__ __align__(16) u16 s_b[128 * 32];
  const int tid = threadIdx.x;
  if (tid < 128) {
    int sv = 0, dv = 0;
    if (tid < mcount) { int e = perm[base + tid]; sv = esrc[e]; dv = edst[e]; }
    s_src[tid] = sv; s_dst[tid] = dv;
  }
  __syncthreads();
  const int lane = tid & 63;
  const int wv = tid >> 6;
  const int wr = wv >> 1, wc = wv & 1;
  const int swz = (lane & 3) ^ ((lane >> 2) & 3) ^ (lane >> 4);
  f32x4 acc[4][4];
#pragma unroll
  for (int m = 0; m < 4; ++m)
#pragma unroll
    for (int n = 0; n < 4; ++n) acc[m][n] = f32x4{0.f, 0.f, 0.f, 0.f};
  const int arow0 = wv * 32;
  const size_t wbase = ((size_t)r << 16) + ((size_t)ny << 15);
  for (int ks = 0; ks < 8; ++ks) {
#pragma unroll
    for (int c2 = 0; c2 < 2; ++c2) {
      const int rowb = arow0 + c2 * 16;
      const int row  = rowb + (lane >> 2);
      const u16* ga = xb + ((size_t)s_src[row] << 8) + (ks << 5) + (swz << 3);
      __builtin_amdgcn_global_load_lds((const GLOBAL_AS uint32_t*)ga,
                                       (LDS_AS uint32_t*)(s_a + rowb * 32), 16, 0, 0);
      const u16* gb = wb + wbase + ((size_t)row << 8) + (ks << 5) + (swz << 3);
      __builtin_amdgcn_global_load_lds((const GLOBAL_AS uint32_t*)gb,
                                       (LDS_AS uint32_t*)(s_b + rowb * 32), 16, 0, 0);
    }
    __syncthreads();
    bf16x8 af[4], bfr[4];
#pragma unroll
    for (int m = 0; m < 4; ++m)
      af[m] = *(const bf16x8*)(s_a + (wr * 64 + m * 16 + (lane & 15)) * 32 + swz * 8);
#pragma unroll
    for (int n = 0; n < 4; ++n)
      bfr[n] = *(const bf16x8*)(s_b + (wc * 64 + n * 16 + (lane & 15)) * 32 + swz * 8);
#pragma unroll
    for (int m = 0; m < 4; ++m)
#pragma unroll
      for (int n = 0; n < 4; ++n)
        acc[m][n] = __builtin_amdgcn_mfma_f32_16x16x32_bf16(af[m], bfr[n], acc[m][n], 0, 0, 0);
    __syncthreads();
  }
  const int colb = ny * 128 + wc * 64 + (lane & 15);
#pragma unroll
  for (int m = 0; m < 4; ++m) {
#pragma unroll
    for (int q = 0; q < 4; ++q) {
      const int rl = wr * 64 + m * 16 + (lane >> 4) * 4 + q;
      if (rl < mcount) {
        float* op = out + (size_t)s_dst[rl] * DIM + colb;
#pragma unroll
        for (int n = 0; n < 4; ++n) atomicAdd(op + n * 16, acc[m][n][q]);
      }
    }
  }
}

// Tier C: correctness-only fallback.
__global__ void k_naive(const float* __restrict__ x, const float* __restrict__ w,
                        const int* __restrict__ esrc, const int* __restrict__ edst,
                        const int* __restrict__ et, float* __restrict__ out)
{
  const int lane = threadIdx.x & 63;
  int gw = (blockIdx.x * blockDim.x + threadIdx.x) >> 6;
  const int nw = (gridDim.x * blockDim.x) >> 6;
  for (int e = gw; e < EDGES; e += nw) {
    const int s = esrc[e], d = edst[e], r = et[e];
    const float* xr = x + (size_t)s * DIM;
    const float* wr0 = w + (size_t)r * DIM * DIM;
    float a[4] = {0.f, 0.f, 0.f, 0.f};
    for (int i = 0; i < DIM; ++i) {
      const float xv = xr[i];
#pragma unroll
      for (int c = 0; c < 4; ++c) a[c] += xv * wr0[(size_t)(lane + c * 64) * DIM + i];
    }
#pragma unroll
    for (int c = 0; c < 4; ++c) atomicAdd(&out[(size_t)d * DIM + lane + c * 64], a[c]);
  }
}

extern "C" void kernel_launch(void* const* d_in, const int* in_sizes, int n_in,
                              void* d_out, int out_size, void* d_ws, size_t ws_size,
                              hipStream_t stream) {
  const float* x    = (const float*)d_in[0];
  const float* w    = (const float*)d_in[1];
  const float* bias = (const float*)d_in[2];
  const int* eidx   = (const int*)d_in[3];
  const int* et     = (const int*)d_in[4];
  const int* esrc = eidx;
  const int* edst = eidx + EDGES;
  float* out = (float*)d_out;

  auto pad = [](size_t v) { return (v + 255) & ~(size_t)255; };

  // Tier A layout
  size_t needA = 0;
  const size_t a_xb = needA;  needA = pad(needA + (size_t)NODES * DIM * 2);
  const size_t a_wb = needA;  needA = pad(needA + (size_t)NREL * DIM * DIM * 2);
  const size_t a_h  = needA;  needA = pad(needA + (size_t)NODES * NJ * 2);
  const size_t a_cnt = needA; needA = pad(needA + (size_t)NODES * 4);
  const size_t a_rp  = needA; needA = pad(needA + ((size_t)NODES + 1) * 4);
  const size_t a_cur = needA; needA = pad(needA + (size_t)NODES * 4);
  const size_t a_bs  = needA; needA = pad(needA + (size_t)SCAN_BLOCKS * 4);
  const size_t a_sg  = needA; needA = pad(needA + (size_t)EDGES * 4);

  // Tier B layout
  size_t needB = 0;
  const size_t b_xb = needB;   needB = pad(needB + (size_t)NODES * DIM * 2);
  const size_t b_wb = needB;   needB = pad(needB + (size_t)NREL * DIM * DIM * 2);
  const size_t b_perm = needB; needB = pad(needB + (size_t)EDGES * 4);
  const size_t b_meta = needB; needB = pad(needB + 64 * 4);

  char* ws = (char*)d_ws;
  if (needA <= ws_size) {
    u16* xb = (u16*)(ws + a_xb);
    u16* wb = (u16*)(ws + a_wb);
    u16* h  = (u16*)(ws + a_h);
    int* cnt = (int*)(ws + a_cnt);
    int* rp  = (int*)(ws + a_rp);
    int* cur = (int*)(ws + a_cur);
    int* bs  = (int*)(ws + a_bs);
    int* sg  = (int*)(ws + a_sg);

    const int n4 = NODES * DIM / 4 + NREL * DIM * DIM / 4;
    k_cvt2<<<(n4 + 255) / 256, 256, 0, stream>>>(x, w, xb, wb);
    (void)hipMemsetAsync(cnt, 0, (size_t)NODES * 4, stream);
    k_hist2<<<3125, 256, 0, stream>>>(edst, cnt);
    k_bsum<<<SCAN_BLOCKS, 256, 0, stream>>>(cnt, bs);
    k_bscan<<<1, 256, 0, stream>>>(bs);
    k_scan2<<<SCAN_BLOCKS, 256, 0, stream>>>(cnt, bs, rp, cur);
    k_scatter2<<<3125, 256, 0, stream>>>(esrc, edst, et, cur, sg);
    k_gemm<<<392 * 16, 256, 0, stream>>>(xb, wb, h);
    k_reduce<<<(NODES * 64 + 255) / 256, 256, 0, stream>>>(h, rp, sg, bias, out);
  } else if (needB <= ws_size) {
    u16* xb  = (u16*)(ws + b_xb);
    u16* wbb = (u16*)(ws + b_wb);
    int* perm = (int*)(ws + b_perm);
    int* meta = (int*)(ws + b_meta);
    k_init_out<<<12500, 256, 0, stream>>>(out, bias);
    k_cvt<<<12500, 256, 0, stream>>>(x, xb, NODES * DIM / 4);
    k_cvt<<<512, 256, 0, stream>>>(w, wbb, NREL * DIM * DIM / 4);
    k_zero8<<<1, 64, 0, stream>>>(meta);
    k_hist<<<SORT_BLOCKS, 256, 0, stream>>>(et, meta);
    k_scan<<<1, 1, 0, stream>>>(meta);
    k_scatter<<<SORT_BLOCKS, 256, 0, stream>>>(et, meta, perm);
    dim3 g(6250, 2, NREL);
    k_gemm_b<<<g, 256, 0, stream>>>(xb, wbb, perm, meta, esrc, edst, out);
  } else {
    k_init_out<<<12500, 256, 0, stream>>>(out, bias);
    k_naive<<<2048, 256, 0, stream>>>(x, w, esrc, edst, et, out);
  }
}

// Round 9
// 249.163 us; speedup vs baseline: 1.5499x; 1.0038x over previous
//
#include <hip/hip_runtime.h>
#include <hip/hip_bf16.h>
#include <stdint.h>

#define NODES 50000
#define EDGES 800000
#define DIM 256
#define NREL 8
#define NJ (NREL * DIM)  // 2048 combined output cols (r*256+o)

typedef unsigned short u16;
typedef __attribute__((ext_vector_type(8))) __bf16 bf16x8;
typedef __attribute__((ext_vector_type(8))) unsigned short us8;
typedef __attribute__((ext_vector_type(4))) float f32x4;

#define GLOBAL_AS __attribute__((address_space(1)))
#define LDS_AS __attribute__((address_space(3)))

__device__ __forceinline__ u16 f2bf(float f) {
  uint32_t u = __builtin_bit_cast(uint32_t, f);
  u += 0x7FFFu + ((u >> 16) & 1u);  // RNE; inputs finite
  return (u16)(u >> 16);
}
__device__ __forceinline__ float bf2f(u16 u) {
  uint32_t t = (uint32_t)u << 16;
  return __builtin_bit_cast(float, t);
}

// Merged x+w bf16 conversion (one launch instead of two)
__global__ void k_cvt2(const float* __restrict__ x, const float* __restrict__ w,
                       u16* __restrict__ xb, u16* __restrict__ wb) {
  const int n4x = NODES * DIM / 4;       // 3,200,000
  const int n4w = NREL * DIM * DIM / 4;  // 131,072
  int i = blockIdx.x * blockDim.x + threadIdx.x;
  if (i < n4x) {
    float4 v = ((const float4*)x)[i];
    ushort4 o;
    o.x = f2bf(v.x); o.y = f2bf(v.y); o.z = f2bf(v.z); o.w = f2bf(v.w);
    ((ushort4*)xb)[i] = o;
  } else if (i < n4x + n4w) {
    const int j = i - n4x;
    float4 v = ((const float4*)w)[j];
    ushort4 o;
    o.x = f2bf(v.x); o.y = f2bf(v.y); o.z = f2bf(v.z); o.w = f2bf(v.w);
    ((ushort4*)wb)[j] = o;
  }
}

__global__ void k_cvt(const float* __restrict__ in, u16* __restrict__ outp, int n4) {
  int i = blockIdx.x * blockDim.x + threadIdx.x;
  if (i >= n4) return;
  float4 v = ((const float4*)in)[i];
  ushort4 o;
  o.x = f2bf(v.x); o.y = f2bf(v.y); o.z = f2bf(v.z); o.w = f2bf(v.w);
  ((ushort4*)outp)[i] = o;
}

// ---------------- Tier A: dense GEMM -> dst-sorted gather-reduce ----------------

// h[n][j] = sum_i xb[n][i] * wb[j][i].
// r8 post-mortem: MfmaUtil 26% with Occupancy 26% (8 waves/CU) — latency/sync
// bound, not throughput (LDS supply caps at ~58% MfmaUtil).  This round: BM=256
// tile, 512 threads / 8 waves (4x2 of 64x64).  LDS/buf = A 16KB + B 8KB; 3 bufs
// = 72KB -> 2 blocks/CU = 16 waves/CU (~50% occ), 2x today's TLP; half as many
// blocks halves prologue/epilogue per output byte.  T4 counted-vmcnt kept:
// stage(ks+1) -> vmcnt(3) (own prev-stage loads landed; new 3 in flight) ->
// s_barrier -> ds_read/MFMA.  3 buffers: stage(ks+2) is issued pre-barrier and
// would race a 2-buffer scheme (r7 analysis).  196 m-tiles padded to 8 XCD
// bands x 25; j in 2 groups of 8 (per-XCD L2: A band 6.4MB/2 passes + B 512KB).
__global__ __launch_bounds__(512) void k_gemm(
    const u16* __restrict__ xb, const u16* __restrict__ wb, u16* __restrict__ h)
{
  const int bid = blockIdx.x;
  const int xcd = bid & 7;
  const int idx = bid >> 3;          // 0..399
  const int jg  = idx / 200;         // 0,1
  const int r2  = idx - jg * 200;
  const int m   = xcd * 25 + (r2 >> 3);
  const int mbase = m * 256;
  if (mbase >= NODES) return;
  const int jbase = (jg * 8 + (r2 & 7)) * 128;

  // 72KB: 3 x [A 8192 u16 | B 4096 u16]; first 64KB reused as 256x128 epilogue tile.
  __shared__ __align__(16) u16 smem[36864];

  const int tid = threadIdx.x;
  const int lane = tid & 63;
  const int wv = tid >> 6;           // 0..7
  const int wr = wv >> 1, wc = wv & 1;
  const int swz = (lane & 3) ^ ((lane >> 2) & 3) ^ (lane >> 4);  // 16B-chunk idx

  f32x4 acc[4][4];
#pragma unroll
  for (int mm = 0; mm < 4; ++mm)
#pragma unroll
    for (int n = 0; n < 4; ++n) acc[mm][n] = f32x4{0.f, 0.f, 0.f, 0.f};

  const int arow0 = wv * 32;  // this wave stages A rows [arow0, arow0+32)
  const int brow0 = wv * 16;  // and B rows [brow0, brow0+16)

  auto STAGE = [&](int buf, int ks) {
    u16* sa = smem + buf * 12288;
    u16* sb = sa + 8192;
#pragma unroll
    for (int c2 = 0; c2 < 2; ++c2) {
      const int rowb = arow0 + c2 * 16;
      const int row  = rowb + (lane >> 2);
      const int ar = min(mbase + row, NODES - 1);  // clamp last tile
      const u16* ga = xb + ((size_t)ar << 8) + (ks << 5) + (swz << 3);
      __builtin_amdgcn_global_load_lds((const GLOBAL_AS uint32_t*)ga,
                                       (LDS_AS uint32_t*)(sa + rowb * 32), 16, 0, 0);
    }
    const int brow = brow0 + (lane >> 2);
    const u16* gb = wb + ((size_t)(jbase + brow) << 8) + (ks << 5) + (swz << 3);
    __builtin_amdgcn_global_load_lds((const GLOBAL_AS uint32_t*)gb,
                                     (LDS_AS uint32_t*)(sb + brow0 * 32), 16, 0, 0);
  };

  STAGE(0, 0);  // 3 loads in flight
#pragma unroll
  for (int ks = 0; ks < 8; ++ks) {
    if (ks < 7) {
      STAGE((ks + 1) % 3, ks + 1);                       // +3 loads (6 in flight)
      asm volatile("s_waitcnt vmcnt(3)" ::: "memory");   // prev stage landed
    } else {
      asm volatile("s_waitcnt vmcnt(0)" ::: "memory");   // final stage landed
    }
    __builtin_amdgcn_s_barrier();                        // no vmcnt(0) drain here

    const u16* sa = smem + (ks % 3) * 12288;
    const u16* sb = sa + 8192;
    bf16x8 af[4], bfr[4];
#pragma unroll
    for (int mm = 0; mm < 4; ++mm)
      af[mm] = *(const bf16x8*)(sa + (wr * 64 + mm * 16 + (lane & 15)) * 32 + swz * 8);
#pragma unroll
    for (int n = 0; n < 4; ++n)
      bfr[n] = *(const bf16x8*)(sb + (wc * 64 + n * 16 + (lane & 15)) * 32 + swz * 8);
#pragma unroll
    for (int mm = 0; mm < 4; ++mm)
#pragma unroll
      for (int n = 0; n < 4; ++n)
        acc[mm][n] = __builtin_amdgcn_mfma_f32_16x16x32_bf16(af[mm], bfr[n], acc[mm][n], 0, 0, 0);
  }
  __syncthreads();  // all waves done reading bufs before tile overwrite

  // Epilogue: acc -> 256x128 LDS tile (XOR key: 4 simultaneous rows hit disjoint
  // bank quartets), then coalesced 16B stores.
  u16* tile = smem;  // 256x128 u16 = 64KB
#pragma unroll
  for (int mm = 0; mm < 4; ++mm) {
#pragma unroll
    for (int q = 0; q < 4; ++q) {
      const int rt = wr * 64 + mm * 16 + (lane >> 4) * 4 + q;
      const int key = ((rt >> 2) & 3) << 4;
#pragma unroll
      for (int n = 0; n < 4; ++n) {
        const int ct = wc * 64 + n * 16 + (lane & 15);
        tile[rt * 128 + (ct ^ key)] = f2bf(acc[mm][n][q]);
      }
    }
  }
  __syncthreads();
#pragma unroll
  for (int i = 0; i < 8; ++i) {
    const int c = tid + i * 512;
    const int row = c >> 4, chunk = c & 15;
    const int grow = mbase + row;
    if (grow < NODES) {
      const int key = ((row >> 2) & 3) << 4;
      const us8 v = *(const us8*)(tile + row * 128 + ((chunk * 8) ^ key));
      *((us8*)(h + (size_t)grow * NJ + jbase) + chunk) = v;
    }
  }
}

// ---- counting sort by dst (50K bins). Scan = 3 small multi-block kernels
// (r5 lesson: single-block scan was 124us at 0.15% occupancy). ----
#define SCAN_BLOCKS 196  // ceil(50000/256)

__global__ void k_hist2(const int* __restrict__ edst, int* __restrict__ cnt) {
  int e = blockIdx.x * blockDim.x + threadIdx.x;
  if (e < EDGES) atomicAdd(&cnt[edst[e]], 1);
}
__global__ void k_bsum(const int* __restrict__ cnt, int* __restrict__ bs) {
  int i = blockIdx.x * blockDim.x + threadIdx.x;
  int v = (i < NODES) ? cnt[i] : 0;
#pragma unroll
  for (int o = 32; o; o >>= 1) v += __shfl_down(v, o);
  __shared__ int wsum[4];
  if ((threadIdx.x & 63) == 0) wsum[threadIdx.x >> 6] = v;
  __syncthreads();
  if (threadIdx.x == 0) bs[blockIdx.x] = wsum[0] + wsum[1] + wsum[2] + wsum[3];
}
__global__ void k_bscan(int* __restrict__ bs) {  // exclusive scan of SCAN_BLOCKS, 1 block
  __shared__ int tmp[SCAN_BLOCKS];
  int t = threadIdx.x;
  if (t < SCAN_BLOCKS) tmp[t] = bs[t];
  __syncthreads();
  if (t == 0) {
    int s = 0;
    for (int i = 0; i < SCAN_BLOCKS; ++i) { int c = tmp[i]; tmp[i] = s; s += c; }
  }
  __syncthreads();
  if (t < SCAN_BLOCKS) bs[t] = tmp[t];
}
__global__ void k_scan2(const int* __restrict__ cnt, const int* __restrict__ bs,
                        int* __restrict__ row_ptr, int* __restrict__ cur) {
  int t = threadIdx.x;
  int i = blockIdx.x * blockDim.x + t;
  int v = (i < NODES) ? cnt[i] : 0;
  __shared__ int tmp[256];
  tmp[t] = v;
  __syncthreads();
  for (int o = 1; o < 256; o <<= 1) {  // Hillis-Steele inclusive
    int u = (t >= o) ? tmp[t - o] : 0;
    __syncthreads();
    tmp[t] += u;
    __syncthreads();
  }
  int val = bs[blockIdx.x] + tmp[t] - v;  // exclusive
  if (i <= NODES) row_ptr[i] = val;       // row_ptr[NODES] lands on EDGES
  if (i < NODES) cur[i] = val;
}
__global__ void k_scatter2(const int* __restrict__ esrc, const int* __restrict__ edst,
                           const int* __restrict__ et, int* __restrict__ cur,
                           int* __restrict__ sg) {
  int e = blockIdx.x * blockDim.x + threadIdx.x;
  if (e < EDGES) {
    int p = atomicAdd(&cur[edst[e]], 1);  // in-bin order irrelevant (sum commutes)
    sg[p] = esrc[e] * NREL + et[e];       // h row index
  }
}

// One wave per dst node: gather ~deg(16) rows of h (512B each), f32-accumulate,
// +bias, single coalesced row write (nt). 8-deep gather unroll for MLP.
__global__ __launch_bounds__(256) void k_reduce(
    const u16* __restrict__ h, const int* __restrict__ row_ptr,
    const int* __restrict__ sg, const float* __restrict__ bias,
    float* __restrict__ out)
{
  const int wid = (int)((blockIdx.x * blockDim.x + threadIdx.x) >> 6);
  if (wid >= NODES) return;
  const int lane = threadIdx.x & 63;
  const int lo = row_ptr[wid], hi = row_ptr[wid + 1];
  const u16* hb = h + lane * 4;

  float a0 = 0.f, a1 = 0.f, a2 = 0.f, a3 = 0.f;
  int e = lo;
  for (; e + 8 <= hi; e += 8) {  // 8 independent 512B gathers in flight
    const ushort4 v0 = *(const ushort4*)(hb + ((size_t)sg[e] << 8));
    const ushort4 v1 = *(const ushort4*)(hb + ((size_t)sg[e + 1] << 8));
    const ushort4 v2 = *(const ushort4*)(hb + ((size_t)sg[e + 2] << 8));
    const ushort4 v3 = *(const ushort4*)(hb + ((size_t)sg[e + 3] << 8));
    const ushort4 v4 = *(const ushort4*)(hb + ((size_t)sg[e + 4] << 8));
    const ushort4 v5 = *(const ushort4*)(hb + ((size_t)sg[e + 5] << 8));
    const ushort4 v6 = *(const ushort4*)(hb + ((size_t)sg[e + 6] << 8));
    const ushort4 v7 = *(const ushort4*)(hb + ((size_t)sg[e + 7] << 8));
    a0 += ((bf2f(v0.x) + bf2f(v1.x)) + (bf2f(v2.x) + bf2f(v3.x))) +
          ((bf2f(v4.x) + bf2f(v5.x)) + (bf2f(v6.x) + bf2f(v7.x)));
    a1 += ((bf2f(v0.y) + bf2f(v1.y)) + (bf2f(v2.y) + bf2f(v3.y))) +
          ((bf2f(v4.y) + bf2f(v5.y)) + (bf2f(v6.y) + bf2f(v7.y)));
    a2 += ((bf2f(v0.z) + bf2f(v1.z)) + (bf2f(v2.z) + bf2f(v3.z))) +
          ((bf2f(v4.z) + bf2f(v5.z)) + (bf2f(v6.z) + bf2f(v7.z)));
    a3 += ((bf2f(v0.w) + bf2f(v1.w)) + (bf2f(v2.w) + bf2f(v3.w))) +
          ((bf2f(v4.w) + bf2f(v5.w)) + (bf2f(v6.w) + bf2f(v7.w)));
  }
  for (; e + 2 <= hi; e += 2) {
    const ushort4 v0 = *(const ushort4*)(hb + ((size_t)sg[e] << 8));
    const ushort4 v1 = *(const ushort4*)(hb + ((size_t)sg[e + 1] << 8));
    a0 += bf2f(v0.x) + bf2f(v1.x);
    a1 += bf2f(v0.y) + bf2f(v1.y);
    a2 += bf2f(v0.z) + bf2f(v1.z);
    a3 += bf2f(v0.w) + bf2f(v1.w);
  }
  if (e < hi) {
    const ushort4 v = *(const ushort4*)(hb + ((size_t)sg[e] << 8));
    a0 += bf2f(v.x); a1 += bf2f(v.y); a2 += bf2f(v.z); a3 += bf2f(v.w);
  }
  const float4 b = ((const float4*)bias)[lane];
  f32x4 o = {a0 + b.x, a1 + b.y, a2 + b.z, a3 + b.w};
  __builtin_nontemporal_store(o, (f32x4*)out + (size_t)wid * 64 + lane);
}

// ---------------- Tier B: round-2 path (per-relation gathered GEMM + atomics) ----------------

__global__ void k_init_out(float* __restrict__ out, const float* __restrict__ bias) {
  int i = blockIdx.x * blockDim.x + threadIdx.x;
  ((float4*)out)[i] = ((const float4*)bias)[i & 63];
}
__global__ void k_zero8(int* __restrict__ meta) {
  if (threadIdx.x < 8) meta[threadIdx.x] = 0;
}
#define SORT_BLOCKS 256
#define SORT_CHUNK ((EDGES + SORT_BLOCKS - 1) / SORT_BLOCKS)
__global__ void k_hist(const int* __restrict__ et, int* __restrict__ meta) {
  __shared__ int lh[NREL];
  if (threadIdx.x < NREL) lh[threadIdx.x] = 0;
  __syncthreads();
  const int lo = blockIdx.x * SORT_CHUNK, hi = min(EDGES, lo + SORT_CHUNK);
  for (int e = lo + threadIdx.x; e < hi; e += blockDim.x) atomicAdd(&lh[et[e]], 1);
  __syncthreads();
  if (threadIdx.x < NREL && lh[threadIdx.x]) atomicAdd(&meta[threadIdx.x], lh[threadIdx.x]);
}
__global__ void k_scan(int* __restrict__ meta) {
  if (threadIdx.x == 0) {
    int s = 0;
    for (int r = 0; r < NREL; ++r) { meta[8 + r] = s; meta[17 + r] = s; s += meta[r]; }
    meta[16] = s;
  }
}
__global__ void k_scatter(const int* __restrict__ et, int* __restrict__ meta,
                          int* __restrict__ perm) {
  __shared__ int lh[NREL];
  __shared__ int lc[NREL];
  if (threadIdx.x < NREL) lh[threadIdx.x] = 0;
  __syncthreads();
  const int lo = blockIdx.x * SORT_CHUNK, hi = min(EDGES, lo + SORT_CHUNK);
  for (int e = lo + threadIdx.x; e < hi; e += blockDim.x) atomicAdd(&lh[et[e]], 1);
  __syncthreads();
  if (threadIdx.x < NREL) {
    const int c = lh[threadIdx.x];
    lc[threadIdx.x] = c ? atomicAdd(&meta[17 + threadIdx.x], c) : 0;
  }
  __syncthreads();
  for (int e = lo + threadIdx.x; e < hi; e += blockDim.x) {
    const int p = atomicAdd(&lc[et[e]], 1);
    perm[p] = e;
  }
}
__global__ __launch_bounds__(256) void k_gemm_b(
    const u16* __restrict__ xb, const u16* __restrict__ wb,
    const int* __restrict__ perm, const int* __restrict__ meta,
    const int* __restrict__ esrc, const int* __restrict__ edst,
    float* __restrict__ out)
{
  const int r = blockIdx.z;
  const int estart = meta[8 + r], eend = meta[9 + r];
  const int base = estart + (int)blockIdx.x * 128;
  if (base >= eend) return;
  const int mcount = min(128, eend - base);
  const int ny = blockIdx.y;
  __shared__ int s_src[128];
  __shared__ int s_dst[128];
  __shared__ __align__(16) u16 s_a[128 * 32];
  __shared__ __align__(16) u16 s_b[128 * 32];
  const int tid = threadIdx.x;
  if (tid < 128) {
    int sv = 0, dv = 0;
    if (tid < mcount) { int e = perm[base + tid]; sv = esrc[e]; dv = edst[e]; }
    s_src[tid] = sv; s_dst[tid] = dv;
  }
  __syncthreads();
  const int lane = tid & 63;
  const int wv = tid >> 6;
  const int wr = wv >> 1, wc = wv & 1;
  const int swz = (lane & 3) ^ ((lane >> 2) & 3) ^ (lane >> 4);
  f32x4 acc[4][4];
#pragma unroll
  for (int m = 0; m < 4; ++m)
#pragma unroll
    for (int n = 0; n < 4; ++n) acc[m][n] = f32x4{0.f, 0.f, 0.f, 0.f};
  const int arow0 = wv * 32;
  const size_t wbase = ((size_t)r << 16) + ((size_t)ny << 15);
  for (int ks = 0; ks < 8; ++ks) {
#pragma unroll
    for (int c2 = 0; c2 < 2; ++c2) {
      const int rowb = arow0 + c2 * 16;
      const int row  = rowb + (lane >> 2);
      const u16* ga = xb + ((size_t)s_src[row] << 8) + (ks << 5) + (swz << 3);
      __builtin_amdgcn_global_load_lds((const GLOBAL_AS uint32_t*)ga,
                                       (LDS_AS uint32_t*)(s_a + rowb * 32), 16, 0, 0);
      const u16* gb = wb + wbase + ((size_t)row << 8) + (ks << 5) + (swz << 3);
      __builtin_amdgcn_global_load_lds((const GLOBAL_AS uint32_t*)gb,
                                       (LDS_AS uint32_t*)(s_b + rowb * 32), 16, 0, 0);
    }
    __syncthreads();
    bf16x8 af[4], bfr[4];
#pragma unroll
    for (int m = 0; m < 4; ++m)
      af[m] = *(const bf16x8*)(s_a + (wr * 64 + m * 16 + (lane & 15)) * 32 + swz * 8);
#pragma unroll
    for (int n = 0; n < 4; ++n)
      bfr[n] = *(const bf16x8*)(s_b + (wc * 64 + n * 16 + (lane & 15)) * 32 + swz * 8);
#pragma unroll
    for (int m = 0; m < 4; ++m)
#pragma unroll
      for (int n = 0; n < 4; ++n)
        acc[m][n] = __builtin_amdgcn_mfma_f32_16x16x32_bf16(af[m], bfr[n], acc[m][n], 0, 0, 0);
    __syncthreads();
  }
  const int colb = ny * 128 + wc * 64 + (lane & 15);
#pragma unroll
  for (int m = 0; m < 4; ++m) {
#pragma unroll
    for (int q = 0; q < 4; ++q) {
      const int rl = wr * 64 + m * 16 + (lane >> 4) * 4 + q;
      if (rl < mcount) {
        float* op = out + (size_t)s_dst[rl] * DIM + colb;
#pragma unroll
        for (int n = 0; n < 4; ++n) atomicAdd(op + n * 16, acc[m][n][q]);
      }
    }
  }
}

// Tier C: correctness-only fallback.
__global__ void k_naive(const float* __restrict__ x, const float* __restrict__ w,
                        const int* __restrict__ esrc, const int* __restrict__ edst,
                        const int* __restrict__ et, float* __restrict__ out)
{
  const int lane = threadIdx.x & 63;
  int gw = (blockIdx.x * blockDim.x + threadIdx.x) >> 6;
  const int nw = (gridDim.x * blockDim.x) >> 6;
  for (int e = gw; e < EDGES; e += nw) {
    const int s = esrc[e], d = edst[e], r = et[e];
    const float* xr = x + (size_t)s * DIM;
    const float* wr0 = w + (size_t)r * DIM * DIM;
    float a[4] = {0.f, 0.f, 0.f, 0.f};
    for (int i = 0; i < DIM; ++i) {
      const float xv = xr[i];
#pragma unroll
      for (int c = 0; c < 4; ++c) a[c] += xv * wr0[(size_t)(lane + c * 64) * DIM + i];
    }
#pragma unroll
    for (int c = 0; c < 4; ++c) atomicAdd(&out[(size_t)d * DIM + lane + c * 64], a[c]);
  }
}

extern "C" void kernel_launch(void* const* d_in, const int* in_sizes, int n_in,
                              void* d_out, int out_size, void* d_ws, size_t ws_size,
                              hipStream_t stream) {
  const float* x    = (const float*)d_in[0];
  const float* w    = (const float*)d_in[1];
  const float* bias = (const float*)d_in[2];
  const int* eidx   = (const int*)d_in[3];
  const int* et     = (const int*)d_in[4];
  const int* esrc = eidx;
  const int* edst = eidx + EDGES;
  float* out = (float*)d_out;

  auto pad = [](size_t v) { return (v + 255) & ~(size_t)255; };

  // Tier A layout
  size_t needA = 0;
  const size_t a_xb = needA;  needA = pad(needA + (size_t)NODES * DIM * 2);
  const size_t a_wb = needA;  needA = pad(needA + (size_t)NREL * DIM * DIM * 2);
  const size_t a_h  = needA;  needA = pad(needA + (size_t)NODES * NJ * 2);
  const size_t a_cnt = needA; needA = pad(needA + (size_t)NODES * 4);
  const size_t a_rp  = needA; needA = pad(needA + ((size_t)NODES + 1) * 4);
  const size_t a_cur = needA; needA = pad(needA + (size_t)NODES * 4);
  const size_t a_bs  = needA; needA = pad(needA + (size_t)SCAN_BLOCKS * 4);
  const size_t a_sg  = needA; needA = pad(needA + (size_t)EDGES * 4);

  // Tier B layout
  size_t needB = 0;
  const size_t b_xb = needB;   needB = pad(needB + (size_t)NODES * DIM * 2);
  const size_t b_wb = needB;   needB = pad(needB + (size_t)NREL * DIM * DIM * 2);
  const size_t b_perm = needB; needB = pad(needB + (size_t)EDGES * 4);
  const size_t b_meta = needB; needB = pad(needB + 64 * 4);

  char* ws = (char*)d_ws;
  if (needA <= ws_size) {
    u16* xb = (u16*)(ws + a_xb);
    u16* wb = (u16*)(ws + a_wb);
    u16* h  = (u16*)(ws + a_h);
    int* cnt = (int*)(ws + a_cnt);
    int* rp  = (int*)(ws + a_rp);
    int* cur = (int*)(ws + a_cur);
    int* bs  = (int*)(ws + a_bs);
    int* sg  = (int*)(ws + a_sg);

    const int n4 = NODES * DIM / 4 + NREL * DIM * DIM / 4;
    k_cvt2<<<(n4 + 255) / 256, 256, 0, stream>>>(x, w, xb, wb);
    (void)hipMemsetAsync(cnt, 0, (size_t)NODES * 4, stream);
    k_hist2<<<3125, 256, 0, stream>>>(edst, cnt);
    k_bsum<<<SCAN_BLOCKS, 256, 0, stream>>>(cnt, bs);
    k_bscan<<<1, 256, 0, stream>>>(bs);
    k_scan2<<<SCAN_BLOCKS, 256, 0, stream>>>(cnt, bs, rp, cur);
    k_scatter2<<<3125, 256, 0, stream>>>(esrc, edst, et, cur, sg);
    k_gemm<<<8 * 400, 512, 0, stream>>>(xb, wb, h);   // 8 XCD bands x (25 m x 16 j)
    k_reduce<<<(NODES * 64 + 255) / 256, 256, 0, stream>>>(h, rp, sg, bias, out);
  } else if (needB <= ws_size) {
    u16* xb  = (u16*)(ws + b_xb);
    u16* wbb = (u16*)(ws + b_wb);
    int* perm = (int*)(ws + b_perm);
    int* meta = (int*)(ws + b_meta);
    k_init_out<<<12500, 256, 0, stream>>>(out, bias);
    k_cvt<<<12500, 256, 0, stream>>>(x, xb, NODES * DIM / 4);
    k_cvt<<<512, 256, 0, stream>>>(w, wbb, NREL * DIM * DIM / 4);
    k_zero8<<<1, 64, 0, stream>>>(meta);
    k_hist<<<SORT_BLOCKS, 256, 0, stream>>>(et, meta);
    k_scan<<<1, 1, 0, stream>>>(meta);
    k_scatter<<<SORT_BLOCKS, 256, 0, stream>>>(et, meta, perm);
    dim3 g(6250, 2, NREL);
    k_gemm_b<<<g, 256, 0, stream>>>(xb, wbb, perm, meta, esrc, edst, out);
  } else {
    k_init_out<<<12500, 256, 0, stream>>>(out, bias);
    k_naive<<<2048, 256, 0, stream>>>(x, w, esrc, edst, et, out);
  }
}